// Round 3
// baseline (1051.319 us; speedup 1.0000x reference)
//
#include <hip/hip_runtime.h>
#include <hip/hip_bf16.h>

#define NP 16384   // H*W
#define NB 4

typedef __hip_bfloat16 bf16;
typedef unsigned short u16;
__device__ __forceinline__ float bf2f(const bf16 v) { return __bfloat162float(v); }

template <bool F32>
__device__ __forceinline__ float ldin(const void* p, size_t i) {
  return F32 ? ((const float*)p)[i] : bf2f(((const bf16*)p)[i]);
}

// ---------------------------------------------------------------------------
// K0: dtype detect. bf16 data -> even u16 elements have sane exponents.
// flag=1 -> fp32 inputs, flag=0 -> bf16 inputs.
// ---------------------------------------------------------------------------
__global__ __launch_bounds__(256) void k_detect(const void* xp, int* flag) {
  int tid = threadIdx.x;
  const u16* u = (const u16*)xp;
  int sane = 0;
  for (int i = tid; i < 1024; i += 256) {
    u16 h = u[2 * i];
    int e = (h >> 7) & 0xFF;
    if ((e >= 97 && e <= 157) || h == 0 || h == 0x8000) sane++;
  }
  __shared__ int sh[256];
  sh[tid] = sane;
  __syncthreads();
  for (int s = 128; s > 0; s >>= 1) {
    if (tid < s) sh[tid] += sh[tid + s];
    __syncthreads();
  }
  if (tid == 0) flag[0] = (sh[0] < 900) ? 1 : 0;
}

// ---------------------------------------------------------------------------
// K1: maxpool2x2(fb) -> conv1x1 + bias -> Y (bf16, pre-BN)
// ---------------------------------------------------------------------------
template <bool F32>
__global__ __launch_bounds__(256) void k_pool_conv(
    const int* __restrict__ flag, const void* __restrict__ fb,
    const void* __restrict__ wconv, const void* __restrict__ bconv,
    bf16* __restrict__ Y) {
  if ((*flag == 1) != F32) return;
  __shared__ float wS[4096];
  __shared__ float bS[64];
  int tid = threadIdx.x;
  for (int i = tid; i < 4096; i += 256) wS[i] = ldin<F32>(wconv, i);
  if (tid < 64) bS[tid] = ldin<F32>(bconv, tid);
  __syncthreads();
  int p = blockIdx.x * 256 + tid;
  int b = p >> 14, n = p & 16383;
  int h = n >> 7, w = n & 127;
  float acc[64];
#pragma unroll
  for (int o = 0; o < 64; ++o) acc[o] = bS[o];
  for (int c = 0; c < 64; ++c) {
    size_t base = ((size_t)((b * 64 + c) * 256 + 2 * h)) * 256 + 2 * w;
    float v0 = ldin<F32>(fb, base), v1 = ldin<F32>(fb, base + 1);
    float v2 = ldin<F32>(fb, base + 256), v3 = ldin<F32>(fb, base + 257);
    float mx = fmaxf(fmaxf(v0, v1), fmaxf(v2, v3));
#pragma unroll
    for (int o = 0; o < 64; ++o) acc[o] = fmaf(wS[o * 64 + c], mx, acc[o]);
  }
  bf16* yb = Y + (size_t)b * 64 * NP + n;
#pragma unroll
  for (int o = 0; o < 64; ++o) yb[(size_t)o * NP] = __float2bfloat16(acc[o]);
}

// ---------------------------------------------------------------------------
// K2: per-channel mean/rstd over (B,H,W) from bf16 Y
// ---------------------------------------------------------------------------
__global__ __launch_bounds__(256) void k_stats(const bf16* __restrict__ Y,
                                               float* __restrict__ MU,
                                               float* __restrict__ RSTD) {
  int o = blockIdx.x, tid = threadIdx.x;
  float s = 0.f, ss = 0.f;
  for (int b = 0; b < NB; ++b) {
    const bf16* p = Y + ((size_t)(b * 64 + o)) * NP;
    for (int i = tid; i < NP; i += 256) {
      float v = bf2f(p[i]);
      s += v; ss = fmaf(v, v, ss);
    }
  }
  for (int off = 32; off > 0; off >>= 1) {
    s += __shfl_down(s, off, 64);
    ss += __shfl_down(ss, off, 64);
  }
  __shared__ float sh[8];
  int wv = tid >> 6, ln = tid & 63;
  if (ln == 0) { sh[wv] = s; sh[4 + wv] = ss; }
  __syncthreads();
  if (tid == 0) {
    float S = sh[0] + sh[1] + sh[2] + sh[3];
    float SS = sh[4] + sh[5] + sh[6] + sh[7];
    const float inv = 1.0f / (NB * NP);
    float mu = S * inv;
    float var = SS * inv - mu * mu;
    MU[o] = mu;
    RSTD[o] = rsqrtf(var + 1e-5f);
  }
}

// K2b: BN scale/shift + scalar header
template <bool F32>
__global__ __launch_bounds__(64) void k_bnscale(
    const int* __restrict__ flag, const void* __restrict__ bng,
    const void* __restrict__ bnb, const float* __restrict__ MU,
    const float* __restrict__ RSTD, float* __restrict__ SCALE,
    float* __restrict__ SHIFT, const void* xg, const void* fg,
    const void* pg, const void* pg2, const void* cg, float* __restrict__ HDR) {
  if ((*flag == 1) != F32) return;
  int o = threadIdx.x;
  float sc = RSTD[o] * ldin<F32>(bng, o);
  SCALE[o] = sc;
  SHIFT[o] = ldin<F32>(bnb, o) - MU[o] * sc;
  if (o == 0) {
    float vpg = ldin<F32>(pg, 0);
    HDR[1] = vpg * ldin<F32>(xg, 0);
    HDR[2] = ldin<F32>(pg2, 0) * ldin<F32>(fg, 0);
    HDR[3] = 2.0f + vpg;
    HDR[4] = ldin<F32>(pg2, 0);
    HDR[5] = ldin<F32>(cg, 0);
  }
}

// K3: Y = relu(Y*scale+shift) in place (bf16)
__global__ __launch_bounds__(256) void k_bnrelu(bf16* __restrict__ Y,
                                                const float* __restrict__ SCALE,
                                                const float* __restrict__ SHIFT) {
  int i = blockIdx.x * 256 + threadIdx.x;
  int c = (i >> 14) & 63;
  float v = fmaf(bf2f(Y[i]), SCALE[c], SHIFT[c]);
  Y[i] = __float2bfloat16(v > 0.f ? v : 0.f);
}

// ---------------------------------------------------------------------------
// K4: q,k,v conv1x1. MODE 0: x-bf16; 1: x-fp32; 2: Y-input flag=0; 3: Y flag=1
// ---------------------------------------------------------------------------
template <int MODE>
__global__ __launch_bounds__(256) void k_qkv(
    const int* __restrict__ flag, const void* __restrict__ inp,
    const void* __restrict__ qw, const void* __restrict__ qb,
    const void* __restrict__ kw, const void* __restrict__ kb,
    const void* __restrict__ vw, const void* __restrict__ vb,
    bf16* __restrict__ Q, bf16* __restrict__ K, bf16* __restrict__ V) {
  constexpr bool WF = (MODE == 1 || MODE == 3);  // external weights fp32?
  if ((*flag == 1) != WF) return;
  __shared__ float qwS[512], kwS[512], vwS[4096];
  __shared__ float qbS[8], kbS[8], vbS[64];
  int tid = threadIdx.x;
  for (int i = tid; i < 512; i += 256) { qwS[i] = ldin<WF>(qw, i); kwS[i] = ldin<WF>(kw, i); }
  for (int i = tid; i < 4096; i += 256) vwS[i] = ldin<WF>(vw, i);
  if (tid < 8) { qbS[tid] = ldin<WF>(qb, tid); kbS[tid] = ldin<WF>(kb, tid); }
  if (tid < 64) vbS[tid] = ldin<WF>(vb, tid);
  __syncthreads();
  int p = blockIdx.x * 256 + tid;
  int b = p >> 14, n = p & 16383;
  float qa[8], ka[8], va[64];
#pragma unroll
  for (int j = 0; j < 8; ++j) { qa[j] = qbS[j]; ka[j] = kbS[j]; }
#pragma unroll
  for (int o = 0; o < 64; ++o) va[o] = vbS[o];
  for (int c = 0; c < 64; ++c) {
    size_t idx = ((size_t)(b * 64 + c)) * NP + n;
    float xv;
    if (MODE == 0) xv = bf2f(((const bf16*)inp)[idx]);
    else if (MODE == 1) xv = ((const float*)inp)[idx];
    else xv = bf2f(((const bf16*)inp)[idx]);  // Y is bf16
#pragma unroll
    for (int j = 0; j < 8; ++j) {
      qa[j] = fmaf(qwS[j * 64 + c], xv, qa[j]);
      ka[j] = fmaf(kwS[j * 64 + c], xv, ka[j]);
    }
#pragma unroll
    for (int o = 0; o < 64; ++o) va[o] = fmaf(vwS[o * 64 + c], xv, va[o]);
  }
#pragma unroll
  for (int j = 0; j < 8; ++j) {
    Q[((size_t)(b * 8 + j)) * NP + n] = __float2bfloat16(qa[j]);
    K[((size_t)(b * 8 + j)) * NP + n] = __float2bfloat16(ka[j]);
  }
#pragma unroll
  for (int o = 0; o < 64; ++o)
    V[((size_t)(b * 64 + o)) * NP + n] = __float2bfloat16(va[o]);
}

// ---------------------------------------------------------------------------
// K5: 128x128 bf16 plane transpose
// ---------------------------------------------------------------------------
__global__ __launch_bounds__(256) void k_transpose(const u16* __restrict__ in,
                                                   u16* __restrict__ out) {
  int tileId = blockIdx.x & 15;
  int plane = blockIdx.x >> 4;
  int th = tileId >> 2, tw = tileId & 3;
  __shared__ u16 t[32][33];
  int lx = threadIdx.x & 31, ly = threadIdx.x >> 5;
  const u16* ip = in + (size_t)plane * NP;
  for (int i = 0; i < 32; i += 8)
    t[ly + i][lx] = ip[(size_t)(th * 32 + ly + i) * 128 + tw * 32 + lx];
  __syncthreads();
  u16* op = out + (size_t)plane * NP;
  for (int i = 0; i < 32; i += 8)
    op[(size_t)(tw * 32 + ly + i) * 128 + th * 32 + lx] = t[lx][ly + i];
}

// ---------------------------------------------------------------------------
// K6: per-pixel joint online softmax stats (m, 1/l) over 256 scores.
// Block (b,h); thread (w, half). e_w: v in half*64..+64. e_h: g parity==half.
// ---------------------------------------------------------------------------
__global__ __launch_bounds__(256) void k_stats_attn(
    const bf16* __restrict__ Q, const bf16* __restrict__ K,
    float* __restrict__ M, float* __restrict__ LI) {
  int b = blockIdx.x >> 7, h = blockIdx.x & 127;
  __shared__ float qrow[8][128], krow[8][128], kg[2][8][128];
  __shared__ float m2[256], l2[256];
  int tid = threadIdx.x;
  for (int i = tid; i < 1024; i += 256) {
    int c = i >> 7, j = i & 127;
    size_t idx = ((size_t)(b * 8 + c)) * NP + (size_t)h * 128 + j;
    qrow[c][j] = bf2f(Q[idx]);
    krow[c][j] = bf2f(K[idx]);
  }
  __syncthreads();
  int w = tid & 127, half = tid >> 7;
  float m = -3.0e38f, l = 0.f;
  for (int v0 = 0; v0 < 64; ++v0) {
    int v = half * 64 + v0;
    float s = 0.f;
#pragma unroll
    for (int c = 0; c < 8; ++c) s = fmaf(qrow[c][w], krow[c][v], s);
    if (s > m) { l = l * __expf(m - s) + 1.f; m = s; }
    else l += __expf(s - m);
  }
  for (int gp = 0; gp < 64; ++gp) {
    __syncthreads();
    for (int i = tid; i < 2048; i += 256) {
      int r = i >> 10, c = (i >> 7) & 7, j = i & 127;
      size_t idx = ((size_t)(b * 8 + c)) * NP + (size_t)(2 * gp + r) * 128 + j;
      kg[r][c][j] = bf2f(K[idx]);
    }
    __syncthreads();
    int g = 2 * gp + half;
    if (g != h) {
      float s = 0.f;
#pragma unroll
      for (int c = 0; c < 8; ++c) s = fmaf(qrow[c][w], kg[half][c][w], s);
      if (s > m) { l = l * __expf(m - s) + 1.f; m = s; }
      else l += __expf(s - m);
    }
  }
  m2[tid] = m; l2[tid] = l;
  __syncthreads();
  if (half == 0) {
    float mo = m2[tid + 128], lo = l2[tid + 128];
    float mm = fmaxf(m, mo);
    float ll = l * __expf(m - mm) + lo * __expf(mo - mm);
    size_t o = (size_t)b * NP + (size_t)h * 128 + w;
    M[o] = mm;
    LI[o] = 1.0f / ll;
  }
}

// ---------------------------------------------------------------------------
// K7: out_w. Block (b,h). Recompute e_w scores, weight = exp(s-M)*LI,
// out_w[c][w] = sum_v wgt * v[c][h][v]. ACC (+)= sc*out_w at [b][c][h][w].
// ---------------------------------------------------------------------------
__global__ __launch_bounds__(128) void k_av_w(
    const int* __restrict__ flag, const bf16* __restrict__ Q,
    const bf16* __restrict__ K, const bf16* __restrict__ V,
    const float* __restrict__ M, const float* __restrict__ LI,
    bf16* __restrict__ ACCd, bf16* __restrict__ ACCw,
    const float* __restrict__ HDR, int scIdx, int accum) {
  bf16* ACC = (*flag == 1) ? ACCw : ACCd;
  int b = blockIdx.x >> 7, h = blockIdx.x & 127;
  __shared__ float qrow[8][128], krow[8][128];
  __shared__ float Vs[64 * 129];
  __shared__ float As[32 * 129];
  __shared__ float Ml[128], Li[128];
  int tid = threadIdx.x;
  for (int i = tid; i < 1024; i += 128) {
    int c = i >> 7, j = i & 127;
    size_t idx = ((size_t)(b * 8 + c)) * NP + (size_t)h * 128 + j;
    qrow[c][j] = bf2f(Q[idx]);
    krow[c][j] = bf2f(K[idx]);
  }
  for (int i = tid; i < 8192; i += 128) {
    int c = i >> 7, j = i & 127;
    Vs[c * 129 + j] = bf2f(V[((size_t)(b * 64 + c)) * NP + (size_t)h * 128 + j]);
  }
  Ml[tid] = M[(size_t)b * NP + (size_t)h * 128 + tid];
  Li[tid] = LI[(size_t)b * NP + (size_t)h * 128 + tid];
  float sc = HDR[scIdx];
  int ig = tid & 7, cg = tid >> 3, c0 = cg * 4;
  int ar = tid >> 2, av = tid & 3;
  bf16* accBase = ACC + (size_t)(b * 64) * NP + (size_t)h * 128;
  for (int chunk = 0; chunk < 4; ++chunk) {
    __syncthreads();
    {
      int w = chunk * 32 + ar;
      float mv = Ml[w], li = Li[w];
      for (int k = 0; k < 32; ++k) {
        int v = av * 32 + k;
        float s = 0.f;
#pragma unroll
        for (int c = 0; c < 8; ++c) s = fmaf(qrow[c][w], krow[c][v], s);
        As[ar * 129 + v] = __expf(s - mv) * li;
      }
    }
    __syncthreads();
    float acc[4][4];
#pragma unroll
    for (int ii = 0; ii < 4; ++ii)
#pragma unroll
      for (int cc = 0; cc < 4; ++cc) acc[ii][cc] = 0.f;
    for (int j = 0; j < 128; ++j) {
      float a[4], vv[4];
#pragma unroll
      for (int ii = 0; ii < 4; ++ii) a[ii] = As[(ig * 4 + ii) * 129 + j];
#pragma unroll
      for (int cc = 0; cc < 4; ++cc) vv[cc] = Vs[(c0 + cc) * 129 + j];
#pragma unroll
      for (int ii = 0; ii < 4; ++ii)
#pragma unroll
        for (int cc = 0; cc < 4; ++cc) acc[ii][cc] = fmaf(a[ii], vv[cc], acc[ii][cc]);
    }
    int i0 = chunk * 32 + ig * 4;
#pragma unroll
    for (int ii = 0; ii < 4; ++ii)
#pragma unroll
      for (int cc = 0; cc < 4; ++cc) {
        size_t oidx = (size_t)(c0 + cc) * NP + (size_t)(i0 + ii);
        float val = sc * acc[ii][cc];
        float prev = accum ? bf2f(accBase[oidx]) : 0.f;
        accBase[oidx] = __float2bfloat16(prev + val);
      }
  }
}

// ---------------------------------------------------------------------------
// K8: out_h. Block (b,w). qcol/kcol from QT/KT row w, V cols from VT row w.
// weight(h,g) = (g==h) ? 0 : exp(s-M[h,w])*LI[h,w].
// out_h[c][h] = sum_g wgt * v[c][g][w]. ACC += sc*out_h at [b][c][h][w].
// ---------------------------------------------------------------------------
__global__ __launch_bounds__(128) void k_av_h(
    const int* __restrict__ flag, const bf16* __restrict__ QT,
    const bf16* __restrict__ KT, const bf16* __restrict__ VT,
    const float* __restrict__ M, const float* __restrict__ LI,
    bf16* __restrict__ ACCd, bf16* __restrict__ ACCw,
    const float* __restrict__ HDR, int scIdx) {
  bf16* ACC = (*flag == 1) ? ACCw : ACCd;
  int b = blockIdx.x >> 7, w = blockIdx.x & 127;
  __shared__ float qcol[8][128], kcol[8][128];
  __shared__ float Vs[64 * 129];
  __shared__ float As[32 * 129];
  __shared__ float Ml[128], Li[128];
  int tid = threadIdx.x;
  for (int i = tid; i < 1024; i += 128) {
    int c = i >> 7, j = i & 127;
    size_t idx = ((size_t)(b * 8 + c)) * NP + (size_t)w * 128 + j;
    qcol[c][j] = bf2f(QT[idx]);
    kcol[c][j] = bf2f(KT[idx]);
  }
  for (int i = tid; i < 8192; i += 128) {
    int c = i >> 7, j = i & 127;
    Vs[c * 129 + j] = bf2f(VT[((size_t)(b * 64 + c)) * NP + (size_t)w * 128 + j]);
  }
  Ml[tid] = M[(size_t)b * NP + (size_t)tid * 128 + w];
  Li[tid] = LI[(size_t)b * NP + (size_t)tid * 128 + w];
  float sc = HDR[scIdx];
  int ig = tid & 7, cg = tid >> 3, c0 = cg * 4;
  int ar = tid >> 2, av = tid & 3;
  bf16* accBase = ACC + (size_t)(b * 64) * NP + w;
  for (int chunk = 0; chunk < 4; ++chunk) {
    __syncthreads();
    {
      int hh = chunk * 32 + ar;
      float mv = Ml[hh], li = Li[hh];
      for (int k = 0; k < 32; ++k) {
        int g = av * 32 + k;
        float s = 0.f;
#pragma unroll
        for (int c = 0; c < 8; ++c) s = fmaf(qcol[c][hh], kcol[c][g], s);
        As[ar * 129 + g] = (g == hh) ? 0.f : __expf(s - mv) * li;
      }
    }
    __syncthreads();
    float acc[4][4];
#pragma unroll
    for (int ii = 0; ii < 4; ++ii)
#pragma unroll
      for (int cc = 0; cc < 4; ++cc) acc[ii][cc] = 0.f;
    for (int j = 0; j < 128; ++j) {
      float a[4], vv[4];
#pragma unroll
      for (int ii = 0; ii < 4; ++ii) a[ii] = As[(ig * 4 + ii) * 129 + j];
#pragma unroll
      for (int cc = 0; cc < 4; ++cc) vv[cc] = Vs[(c0 + cc) * 129 + j];
#pragma unroll
      for (int ii = 0; ii < 4; ++ii)
#pragma unroll
        for (int cc = 0; cc < 4; ++cc) acc[ii][cc] = fmaf(a[ii], vv[cc], acc[ii][cc]);
    }
    int i0 = chunk * 32 + ig * 4;
#pragma unroll
    for (int ii = 0; ii < 4; ++ii)
#pragma unroll
      for (int cc = 0; cc < 4; ++cc) {
        size_t oidx = (size_t)(c0 + cc) * NP + (size_t)(i0 + ii) * 128;
        float prev = bf2f(accBase[oidx]);
        accBase[oidx] = __float2bfloat16(prev + sc * acc[ii][cc]);
      }
  }
}

// ---------------------------------------------------------------------------
// K9: partial Gram of Y (bf16)
// ---------------------------------------------------------------------------
__global__ __launch_bounds__(256) void k_gram(const bf16* __restrict__ Y,
                                              float* __restrict__ GP) {
  int b = blockIdx.x >> 5, ch = blockIdx.x & 31;
  int tid = threadIdx.x;
  __shared__ float fs[64 * 129];
  int cg = tid >> 4, dg = tid & 15;
  float acc[4][4];
#pragma unroll
  for (int i = 0; i < 4; ++i)
#pragma unroll
    for (int jx = 0; jx < 4; ++jx) acc[i][jx] = 0.f;
  const bf16* yb = Y + (size_t)b * 64 * NP + ch * 512;
  for (int t = 0; t < 4; ++t) {
    __syncthreads();
    for (int idx = tid; idx < 8192; idx += 256) {
      int c = idx >> 7, j = idx & 127;
      fs[c * 129 + j] = bf2f(yb[(size_t)c * NP + t * 128 + j]);
    }
    __syncthreads();
    for (int j = 0; j < 128; ++j) {
      float a[4], d[4];
#pragma unroll
      for (int i = 0; i < 4; ++i) a[i] = fs[(cg * 4 + i) * 129 + j];
#pragma unroll
      for (int i = 0; i < 4; ++i) d[i] = fs[(dg * 4 + i) * 129 + j];
#pragma unroll
      for (int i = 0; i < 4; ++i)
#pragma unroll
        for (int jx = 0; jx < 4; ++jx) acc[i][jx] = fmaf(a[i], d[jx], acc[i][jx]);
    }
  }
  float* gp = GP + ((size_t)b * 32 + ch) * 4096;
#pragma unroll
  for (int i = 0; i < 4; ++i)
#pragma unroll
    for (int jx = 0; jx < 4; ++jx)
      gp[(cg * 4 + i) * 64 + dg * 4 + jx] = acc[i][jx];
}

// K10: reduce Gram partials; row softmax of (max-E) == exp(-E)/sum
__global__ __launch_bounds__(256) void k_gram_reduce(const float* __restrict__ GP,
                                                     float* __restrict__ CATT) {
  int b = blockIdx.x, tid = threadIdx.x;
  __shared__ float Es[4096];
  for (int e = tid; e < 4096; e += 256) {
    float s = 0.f;
    for (int k = 0; k < 32; ++k) s += GP[((size_t)b * 32 + k) * 4096 + e];
    Es[e] = s;
  }
  __syncthreads();
  int wv = tid >> 6, ln = tid & 63;
  for (int r = wv; r < 64; r += 4) {
    float v = Es[r * 64 + ln];
    float mn = v;
    for (int off = 32; off; off >>= 1) mn = fminf(mn, __shfl_xor(mn, off, 64));
    float e = __expf(mn - v);
    float s = e;
    for (int off = 32; off; off >>= 1) s += __shfl_xor(s, off, 64);
    CATT[((size_t)b * 64 + r) * 64 + ln] = e / s;
  }
}

// ---------------------------------------------------------------------------
// K11: out = (2+pg)*x + pg2*y + ACC + cg*(catt@y). In-place safe when ACC==out.
// ---------------------------------------------------------------------------
template <bool F32>
__global__ __launch_bounds__(256) void k_final(
    const int* __restrict__ flag, const void* __restrict__ x,
    const bf16* __restrict__ Y, const bf16* __restrict__ ACCd,
    const bf16* __restrict__ ACCw, const float* __restrict__ CATT,
    const float* __restrict__ HDR, void* __restrict__ out) {
  if ((*flag == 1) != F32) return;
  const bf16* ACC = F32 ? ACCw : ACCd;
  __shared__ float att[4096];
  int tid = threadIdx.x;
  int p = blockIdx.x * 256 + tid;
  int b = p >> 14, n = p & 16383;
  for (int i = tid; i < 4096; i += 256) att[i] = CATT[(size_t)b * 4096 + i];
  __syncthreads();
  float yreg[64];
  const bf16* yb = Y + (size_t)b * 64 * NP + n;
#pragma unroll
  for (int d = 0; d < 64; ++d) yreg[d] = bf2f(yb[(size_t)d * NP]);
  float acc[64];
#pragma unroll
  for (int c = 0; c < 64; ++c) acc[c] = 0.f;
  for (int d = 0; d < 64; ++d) {
    float yv = yreg[d];
#pragma unroll
    for (int c = 0; c < 64; ++c) acc[c] = fmaf(att[c * 64 + d], yv, acc[c]);
  }
  float c2pg = HDR[3], fpg2 = HDR[4], fcg = HDR[5];
  size_t base = (size_t)b * 64 * NP + n;
#pragma unroll
  for (int c = 0; c < 64; ++c) {
    size_t idx = base + (size_t)c * NP;
    float xv = ldin<F32>(x, idx);
    float r = c2pg * xv + fpg2 * yreg[c] + bf2f(ACC[idx]) + fcg * acc[c];
    if (F32) ((float*)out)[idx] = r;
    else ((bf16*)out)[idx] = __float2bfloat16(r);
  }
}

// ---------------------------------------------------------------------------
extern "C" void kernel_launch(void* const* d_in, const int* in_sizes, int n_in,
                              void* d_out, int out_size, void* d_ws, size_t ws_size,
                              hipStream_t stream) {
  const void* x = d_in[0];
  const void* fbp = d_in[1];

  char* base = (char*)d_ws;
  int* FLAG = (int*)base;
  float* HDR = (float*)base;
  float* MU = HDR + 16;      // 64
  float* RSTD = MU + 64;     // 64
  float* SCALE = RSTD + 64;  // 64
  float* SHIFT = SCALE + 64; // 64
  char* p = base + 4096;
  bf16* Y = (bf16*)p;        p += 8388608;   // 4.19M bf16
  bf16* Q = (bf16*)p;        p += 1048576;
  bf16* K = (bf16*)p;        p += 1048576;
  bf16* QT = (bf16*)p;       p += 1048576;
  bf16* KT = (bf16*)p;       p += 1048576;
  bf16* V = (bf16*)p;        p += 8388608;
  bf16* VT = (bf16*)p;       p += 8388608;
  float* M = (float*)p;      p += 262144;
  float* LI = (float*)p;     p += 262144;
  bf16* ACCw = (bf16*)p;     // 8 MB, used only when flag=1 (fp32 out)
  bf16* ACCd = (bf16*)d_out; // bf16 path accumulates in d_out
  float* GP = (float*)Q;     // 2 MB, reuses Q/K after module loop
  float* CATT = (float*)QT;  // 64 KB, reuses QT

  k_detect<<<1, 256, 0, stream>>>(x, FLAG);
  k_pool_conv<false><<<256, 256, 0, stream>>>(FLAG, fbp, d_in[2], d_in[3], Y);
  k_pool_conv<true><<<256, 256, 0, stream>>>(FLAG, fbp, d_in[2], d_in[3], Y);
  k_stats<<<64, 256, 0, stream>>>(Y, MU, RSTD);
  k_bnscale<false><<<1, 64, 0, stream>>>(FLAG, d_in[4], d_in[5], MU, RSTD, SCALE,
                                         SHIFT, d_in[12], d_in[19], d_in[20],
                                         d_in[21], d_in[22], HDR);
  k_bnscale<true><<<1, 64, 0, stream>>>(FLAG, d_in[4], d_in[5], MU, RSTD, SCALE,
                                        SHIFT, d_in[12], d_in[19], d_in[20],
                                        d_in[21], d_in[22], HDR);
  k_bnrelu<<<16384, 256, 0, stream>>>(Y, SCALE, SHIFT);

  for (int m = 0; m < 2; ++m) {
    const void *qw, *qb, *kw, *kb, *vw, *vb;
    if (m == 0) {
      qw = d_in[6]; qb = d_in[7]; kw = d_in[8]; kb = d_in[9];
      vw = d_in[10]; vb = d_in[11];
    } else {
      qw = d_in[13]; qb = d_in[14]; kw = d_in[15]; kb = d_in[16];
      vw = d_in[17]; vb = d_in[18];
    }
    if (m == 0) {
      k_qkv<0><<<256, 256, 0, stream>>>(FLAG, x, qw, qb, kw, kb, vw, vb, Q, K, V);
      k_qkv<1><<<256, 256, 0, stream>>>(FLAG, x, qw, qb, kw, kb, vw, vb, Q, K, V);
    } else {
      k_qkv<2><<<256, 256, 0, stream>>>(FLAG, Y, qw, qb, kw, kb, vw, vb, Q, K, V);
      k_qkv<3><<<256, 256, 0, stream>>>(FLAG, Y, qw, qb, kw, kb, vw, vb, Q, K, V);
    }
    k_transpose<<<512, 256, 0, stream>>>((const u16*)Q, (u16*)QT);
    k_transpose<<<512, 256, 0, stream>>>((const u16*)K, (u16*)KT);
    k_transpose<<<4096, 256, 0, stream>>>((const u16*)V, (u16*)VT);
    k_stats_attn<<<512, 256, 0, stream>>>(Q, K, M, LI);
    k_av_w<<<512, 128, 0, stream>>>(FLAG, Q, K, V, M, LI, ACCd, ACCw, HDR,
                                    1 + m, m);
    k_av_h<<<512, 128, 0, stream>>>(FLAG, QT, KT, VT, M, LI, ACCd, ACCw, HDR,
                                    1 + m);
  }

  k_gram<<<128, 256, 0, stream>>>(Y, GP);
  k_gram_reduce<<<4, 256, 0, stream>>>(GP, CATT);
  k_final<false><<<256, 256, 0, stream>>>(FLAG, x, Y, ACCd, ACCw, CATT, HDR, d_out);
  k_final<true><<<256, 256, 0, stream>>>(FLAG, x, Y, ACCd, ACCw, CATT, HDR, d_out);
}

// Round 6
// 770.632 us; speedup vs baseline: 1.3642x; 1.3642x over previous
//
#include <hip/hip_runtime.h>
#include <hip/hip_bf16.h>

#define NP 16384   // H*W
#define NB 4

typedef __hip_bfloat16 bf16;
typedef unsigned short u16;
__device__ __forceinline__ float bf2f(const bf16 v) { return __bfloat162float(v); }
__device__ __forceinline__ bf16 f2bf(float v) { return __float2bfloat16(v); }

template <bool F32>
__device__ __forceinline__ float ldin(const void* p, size_t i) {
  return F32 ? ((const float*)p)[i] : bf2f(((const bf16*)p)[i]);
}

// ---------------------------------------------------------------------------
// K0: dtype detect. bf16 data -> even u16 elements have sane exponents;
// fp32 data -> even u16 are mantissa garbage. flag=1 -> fp32 inputs.
// ---------------------------------------------------------------------------
__global__ __launch_bounds__(256) void k_detect(const void* xp, int* flag) {
  int tid = threadIdx.x;
  const u16* u = (const u16*)xp;
  int sane = 0;
  for (int i = tid; i < 1024; i += 256) {
    u16 h = u[2 * i];
    int e = (h >> 7) & 0xFF;
    if ((e >= 97 && e <= 157) || h == 0 || h == 0x8000) sane++;
  }
  __shared__ int sh[256];
  sh[tid] = sane;
  __syncthreads();
  for (int s = 128; s > 0; s >>= 1) {
    if (tid < s) sh[tid] += sh[tid + s];
    __syncthreads();
  }
  if (tid == 0) flag[0] = (sh[0] < 900) ? 1 : 0;
}

// ---------------------------------------------------------------------------
// K1: maxpool2x2(fb) -> conv1x1+bias -> Y raw (pre-BN, bf16). Tiled 64x64.
// ---------------------------------------------------------------------------
template <bool F32>
__global__ __launch_bounds__(256) void k_pool_conv(
    const int* __restrict__ flag, const void* __restrict__ fb,
    const void* __restrict__ wconv, const void* __restrict__ bconv,
    bf16* __restrict__ Y) {
  if ((*flag == 1) != F32) return;
  __shared__ float wS[4096], bS[64], Xs[4096];
  int tid = threadIdx.x;
  int b = blockIdx.x >> 8, tile = blockIdx.x & 255;
  int n0 = tile * 64;
  for (int i = tid; i < 4096; i += 256) wS[i] = ldin<F32>(wconv, i);
  if (tid < 64) bS[tid] = ldin<F32>(bconv, tid);
  for (int i = tid; i < 4096; i += 256) {
    int c = i >> 6, px = i & 63;
    int n = n0 + px, h = n >> 7, w = n & 127;
    size_t fbase = ((size_t)((b * 64 + c) * 256 + 2 * h)) * 256 + 2 * w;
    float v0 = ldin<F32>(fb, fbase), v1 = ldin<F32>(fb, fbase + 1);
    float v2 = ldin<F32>(fb, fbase + 256), v3 = ldin<F32>(fb, fbase + 257);
    Xs[i] = fmaxf(fmaxf(v0, v1), fmaxf(v2, v3));
  }
  __syncthreads();
  int ty = tid >> 4, tx = tid & 15;
  float acc[4][4];
#pragma unroll
  for (int i = 0; i < 4; ++i) {
    float bv = bS[ty + 16 * i];
#pragma unroll
    for (int j = 0; j < 4; ++j) acc[i][j] = bv;
  }
  for (int c = 0; c < 64; ++c) {
    float xv[4], wv[4];
#pragma unroll
    for (int j = 0; j < 4; ++j) xv[j] = Xs[c * 64 + tx * 4 + j];
#pragma unroll
    for (int i = 0; i < 4; ++i) wv[i] = wS[(ty + 16 * i) * 64 + c];
#pragma unroll
    for (int i = 0; i < 4; ++i)
#pragma unroll
      for (int j = 0; j < 4; ++j) acc[i][j] = fmaf(wv[i], xv[j], acc[i][j]);
  }
#pragma unroll
  for (int i = 0; i < 4; ++i) {
    int ch = ty + 16 * i;
    bf16* yb = Y + (size_t)(b * 64 + ch) * NP + n0 + tx * 4;
#pragma unroll
    for (int j = 0; j < 4; ++j) yb[j] = f2bf(acc[i][j]);
  }
}

// ---------------------------------------------------------------------------
// K2: per-channel mean/rstd over (B,H,W) from raw Y (internal, no flag)
// ---------------------------------------------------------------------------
__global__ __launch_bounds__(256) void k_stats(const bf16* __restrict__ Y,
                                               float* __restrict__ MU,
                                               float* __restrict__ RSTD) {
  int o = blockIdx.x, tid = threadIdx.x;
  float s = 0.f, ss = 0.f;
  for (int b = 0; b < NB; ++b) {
    const bf16* p = Y + ((size_t)(b * 64 + o)) * NP;
    for (int i = tid; i < NP; i += 256) {
      float v = bf2f(p[i]);
      s += v; ss = fmaf(v, v, ss);
    }
  }
  for (int off = 32; off > 0; off >>= 1) {
    s += __shfl_down(s, off, 64);
    ss += __shfl_down(ss, off, 64);
  }
  __shared__ float sh[8];
  int wv = tid >> 6, ln = tid & 63;
  if (ln == 0) { sh[wv] = s; sh[4 + wv] = ss; }
  __syncthreads();
  if (tid == 0) {
    float S = sh[0] + sh[1] + sh[2] + sh[3];
    float SS = sh[4] + sh[5] + sh[6] + sh[7];
    const float inv = 1.0f / (NB * NP);
    float mu = S * inv;
    float var = SS * inv - mu * mu;
    MU[o] = mu;
    RSTD[o] = rsqrtf(var + 1e-5f);
  }
}

// K2b: BN scale/shift + scalar header
template <bool F32>
__global__ __launch_bounds__(64) void k_bnscale(
    const int* __restrict__ flag, const void* __restrict__ bng,
    const void* __restrict__ bnb, const float* __restrict__ MU,
    const float* __restrict__ RSTD, float* __restrict__ SCALE,
    float* __restrict__ SHIFT, const void* xg, const void* fg,
    const void* pg, const void* pg2, const void* cg, float* __restrict__ HDR) {
  if ((*flag == 1) != F32) return;
  int o = threadIdx.x;
  float sc = RSTD[o] * ldin<F32>(bng, o);
  SCALE[o] = sc;
  SHIFT[o] = ldin<F32>(bnb, o) - MU[o] * sc;
  if (o == 0) {
    float vpg = ldin<F32>(pg, 0);
    HDR[1] = vpg * ldin<F32>(xg, 0);
    HDR[2] = ldin<F32>(pg2, 0) * ldin<F32>(fg, 0);
    HDR[3] = 2.0f + vpg;
    HDR[4] = ldin<F32>(pg2, 0);
    HDR[5] = ldin<F32>(cg, 0);
  }
}

// ---------------------------------------------------------------------------
// K4: fused q|k|v conv1x1: 80 out-ch x 128 px per block, 5x8 thread tile.
// BN=true: input is internal bf16 Y (BN+ReLU at staging). BN=false: input is
// external x with dtype F32. Weights always external with dtype F32.
// ---------------------------------------------------------------------------
template <bool F32, bool BN>
__global__ __launch_bounds__(256) void k_conv80(
    const int* __restrict__ flag, const void* __restrict__ inp,
    const float* __restrict__ SCALE, const float* __restrict__ SHIFT,
    const void* __restrict__ qw, const void* __restrict__ qb,
    const void* __restrict__ kw, const void* __restrict__ kb,
    const void* __restrict__ vw, const void* __restrict__ vb,
    bf16* __restrict__ Q, bf16* __restrict__ K, bf16* __restrict__ V) {
  if ((*flag == 1) != F32) return;
  __shared__ float wS[5120], bS[80], Xs[8192];
  int tid = threadIdx.x;
  int b = blockIdx.x >> 7, tile = blockIdx.x & 127;
  int n0 = tile * 128;
  for (int i = tid; i < 512; i += 256) {
    wS[i] = ldin<F32>(qw, i);
    wS[512 + i] = ldin<F32>(kw, i);
  }
  for (int i = tid; i < 4096; i += 256) wS[1024 + i] = ldin<F32>(vw, i);
  if (tid < 8) { bS[tid] = ldin<F32>(qb, tid); bS[8 + tid] = ldin<F32>(kb, tid); }
  if (tid < 64) bS[16 + tid] = ldin<F32>(vb, tid);
  for (int i = tid; i < 8192; i += 256) {
    int c = i >> 7, px = i & 127;
    size_t idx = (size_t)(b * 64 + c) * NP + n0 + px;
    float v;
    if (BN) {
      v = bf2f(((const bf16*)inp)[idx]);
      v = fmaf(v, SCALE[c], SHIFT[c]);
      v = fmaxf(v, 0.f);
    } else {
      v = ldin<F32>(inp, idx);
    }
    Xs[i] = v;
  }
  __syncthreads();
  int ty = tid >> 4, tx = tid & 15;
  float acc[5][8];
#pragma unroll
  for (int i = 0; i < 5; ++i) {
    float bv = bS[ty + 16 * i];
#pragma unroll
    for (int j = 0; j < 8; ++j) acc[i][j] = bv;
  }
  for (int c = 0; c < 64; ++c) {
    float xv[8], wv[5];
#pragma unroll
    for (int j = 0; j < 8; ++j) xv[j] = Xs[c * 128 + tx + 16 * j];
#pragma unroll
    for (int i = 0; i < 5; ++i) wv[i] = wS[(ty + 16 * i) * 64 + c];
#pragma unroll
    for (int i = 0; i < 5; ++i)
#pragma unroll
      for (int j = 0; j < 8; ++j) acc[i][j] = fmaf(wv[i], xv[j], acc[i][j]);
  }
#pragma unroll
  for (int i = 0; i < 5; ++i) {
    int ch = ty + 16 * i;
    bf16* dst;
    size_t base;
    if (ch < 8) { dst = Q; base = (size_t)(b * 8 + ch) * NP; }
    else if (ch < 16) { dst = K; base = (size_t)(b * 8 + ch - 8) * NP; }
    else { dst = V; base = (size_t)(b * 64 + ch - 16) * NP; }
#pragma unroll
    for (int j = 0; j < 8; ++j) dst[base + n0 + tx + 16 * j] = f2bf(acc[i][j]);
  }
}

// ---------------------------------------------------------------------------
// K5: 128x128 bf16 plane transpose (internal)
// ---------------------------------------------------------------------------
__global__ __launch_bounds__(256) void k_transpose(const u16* __restrict__ in,
                                                   u16* __restrict__ out) {
  int tileId = blockIdx.x & 15;
  int plane = blockIdx.x >> 4;
  int th = tileId >> 2, tw = tileId & 3;
  __shared__ u16 t[32][33];
  int lx = threadIdx.x & 31, ly = threadIdx.x >> 5;
  const u16* ip = in + (size_t)plane * NP;
  for (int i = 0; i < 32; i += 8)
    t[ly + i][lx] = ip[(size_t)(th * 32 + ly + i) * 128 + tw * 32 + lx];
  __syncthreads();
  u16* op = out + (size_t)plane * NP;
  for (int i = 0; i < 32; i += 8)
    op[(size_t)(tw * 32 + ly + i) * 128 + th * 32 + lx] = t[lx][ly + i];
}

// ---------------------------------------------------------------------------
// K6a: e_w per-row max/sumexp -> raw stats in MW/LW (internal)
// ---------------------------------------------------------------------------
__global__ __launch_bounds__(256) void k_ew_stats(
    const bf16* __restrict__ Q, const bf16* __restrict__ K,
    float* __restrict__ MW, float* __restrict__ LW) {
  int b = blockIdx.x >> 7, h = blockIdx.x & 127;
  __shared__ float qs[1024], ks[1024], red[256];
  int tid = threadIdx.x;
  for (int i = tid; i < 1024; i += 256) {
    int c = i >> 7, j = i & 127;
    size_t idx = (size_t)(b * 8 + c) * NP + (size_t)h * 128 + j;
    qs[i] = bf2f(Q[idx]);
    ks[i] = bf2f(K[idx]);
  }
  __syncthreads();
  int w = tid & 127, half = tid >> 7;
  float qr[8];
#pragma unroll
  for (int c = 0; c < 8; ++c) qr[c] = qs[c * 128 + w];
  float m = -3.0e38f;
  for (int v0 = 0; v0 < 64; ++v0) {
    int v = half * 64 + v0;
    float s = 0.f;
#pragma unroll
    for (int c = 0; c < 8; ++c) s = fmaf(qr[c], ks[c * 128 + v], s);
    m = fmaxf(m, s);
  }
  red[tid] = m;
  __syncthreads();
  float mj = fmaxf(red[w], red[128 + w]);
  __syncthreads();
  float l = 0.f;
  for (int v0 = 0; v0 < 64; ++v0) {
    int v = half * 64 + v0;
    float s = 0.f;
#pragma unroll
    for (int c = 0; c < 8; ++c) s = fmaf(qr[c], ks[c * 128 + v], s);
    l += __expf(s - mj);
  }
  red[tid] = l;
  __syncthreads();
  if (half == 0) {
    size_t o = (size_t)b * NP + (size_t)h * 128 + w;
    MW[o] = mj;
    LW[o] = red[w] + red[128 + w];
  }
}

// ---------------------------------------------------------------------------
// K6b: e_h per-row stats (diag masked) + in-place combine -> MW=M, LW=1/L
// ---------------------------------------------------------------------------
__global__ __launch_bounds__(256) void k_eh_combine(
    const bf16* __restrict__ QT, const bf16* __restrict__ KT,
    float* __restrict__ MW, float* __restrict__ LW) {
  int b = blockIdx.x >> 7, w = blockIdx.x & 127;
  __shared__ float qs[1024], ks[1024], red[256];
  int tid = threadIdx.x;
  for (int i = tid; i < 1024; i += 256) {
    int c = i >> 7, j = i & 127;
    size_t idx = (size_t)(b * 8 + c) * NP + (size_t)w * 128 + j;
    qs[i] = bf2f(QT[idx]);
    ks[i] = bf2f(KT[idx]);
  }
  __syncthreads();
  int h = tid & 127, half = tid >> 7;
  float qr[8];
#pragma unroll
  for (int c = 0; c < 8; ++c) qr[c] = qs[c * 128 + h];
  float m = -3.0e38f;
  for (int g0 = 0; g0 < 64; ++g0) {
    int g = half * 64 + g0;
    float s = 0.f;
#pragma unroll
    for (int c = 0; c < 8; ++c) s = fmaf(qr[c], ks[c * 128 + g], s);
    if (g == h) s = -1.0e30f;
    m = fmaxf(m, s);
  }
  red[tid] = m;
  __syncthreads();
  float mj = fmaxf(red[h], red[128 + h]);
  __syncthreads();
  float l = 0.f;
  for (int g0 = 0; g0 < 64; ++g0) {
    int g = half * 64 + g0;
    float s = 0.f;
#pragma unroll
    for (int c = 0; c < 8; ++c) s = fmaf(qr[c], ks[c * 128 + g], s);
    l += (g == h) ? 0.f : __expf(s - mj);
  }
  red[tid] = l;
  __syncthreads();
  if (half == 0) {
    size_t o = (size_t)b * NP + (size_t)h * 128 + w;
    float lh = red[h] + red[128 + h];
    float mw = MW[o], lw = LW[o];
    float mm = fmaxf(mw, mj);
    float ll = lw * __expf(mw - mm) + lh * __expf(mj - mm);
    MW[o] = mm;
    LW[o] = 1.0f / ll;
  }
}

// ---------------------------------------------------------------------------
// K7: out_w. ACC (in d_out, dtype per F32) (+)= sc*out_w at [b][c][h][w].
// ---------------------------------------------------------------------------
template <bool F32>
__global__ __launch_bounds__(128) void k_av_w(
    const int* __restrict__ flag, const bf16* __restrict__ Q,
    const bf16* __restrict__ K, const bf16* __restrict__ V,
    const float* __restrict__ M, const float* __restrict__ LI,
    void* __restrict__ ACCv, const float* __restrict__ HDR, int scIdx,
    int accum) {
  if ((*flag == 1) != F32) return;
  int b = blockIdx.x >> 7, h = blockIdx.x & 127;
  __shared__ float qrow[8][128], krow[8][128];
  __shared__ float Vs[64 * 129];
  __shared__ float As[32 * 129];
  __shared__ float Ml[128], Li[128];
  int tid = threadIdx.x;
  for (int i = tid; i < 1024; i += 128) {
    int c = i >> 7, j = i & 127;
    size_t idx = ((size_t)(b * 8 + c)) * NP + (size_t)h * 128 + j;
    qrow[c][j] = bf2f(Q[idx]);
    krow[c][j] = bf2f(K[idx]);
  }
  for (int i = tid; i < 8192; i += 128) {
    int c = i >> 7, j = i & 127;
    Vs[c * 129 + j] = bf2f(V[((size_t)(b * 64 + c)) * NP + (size_t)h * 128 + j]);
  }
  Ml[tid] = M[(size_t)b * NP + (size_t)h * 128 + tid];
  Li[tid] = LI[(size_t)b * NP + (size_t)h * 128 + tid];
  float sc = HDR[scIdx];
  int ig = tid & 7, cg = tid >> 3, c0 = cg * 4;
  int ar = tid >> 2, av = tid & 3;
  size_t outBase = (size_t)(b * 64) * NP + (size_t)h * 128;
  for (int chunk = 0; chunk < 4; ++chunk) {
    __syncthreads();
    {
      int w = chunk * 32 + ar;
      float mv = Ml[w], li = Li[w];
      for (int k = 0; k < 32; ++k) {
        int v = av * 32 + k;
        float s = 0.f;
#pragma unroll
        for (int c = 0; c < 8; ++c) s = fmaf(qrow[c][w], krow[c][v], s);
        As[ar * 129 + v] = __expf(s - mv) * li;
      }
    }
    __syncthreads();
    float acc[4][4];
#pragma unroll
    for (int ii = 0; ii < 4; ++ii)
#pragma unroll
      for (int cc = 0; cc < 4; ++cc) acc[ii][cc] = 0.f;
    for (int j = 0; j < 128; ++j) {
      float a[4], vv[4];
#pragma unroll
      for (int ii = 0; ii < 4; ++ii) a[ii] = As[(ig * 4 + ii) * 129 + j];
#pragma unroll
      for (int cc = 0; cc < 4; ++cc) vv[cc] = Vs[(c0 + cc) * 129 + j];
#pragma unroll
      for (int ii = 0; ii < 4; ++ii)
#pragma unroll
        for (int cc = 0; cc < 4; ++cc) acc[ii][cc] = fmaf(a[ii], vv[cc], acc[ii][cc]);
    }
    int i0 = chunk * 32 + ig * 4;
#pragma unroll
    for (int ii = 0; ii < 4; ++ii)
#pragma unroll
      for (int cc = 0; cc < 4; ++cc) {
        size_t oidx = outBase + (size_t)(c0 + cc) * NP + (size_t)(i0 + ii);
        float val = sc * acc[ii][cc];
        if (F32) {
          float* A = (float*)ACCv;
          A[oidx] = (accum ? A[oidx] : 0.f) + val;
        } else {
          bf16* A = (bf16*)ACCv;
          A[oidx] = f2bf((accum ? bf2f(A[oidx]) : 0.f) + val);
        }
      }
  }
}

// ---------------------------------------------------------------------------
// K8: out_h. weight(h,g) = (g==h)?0:exp(s-M[h,w])*LI[h,w]. ACC += sc*out_h.
// ---------------------------------------------------------------------------
template <bool F32>
__global__ __launch_bounds__(128) void k_av_h(
    const int* __restrict__ flag, const bf16* __restrict__ QT,
    const bf16* __restrict__ KT, const bf16* __restrict__ VT,
    const float* __restrict__ M, const float* __restrict__ LI,
    void* __restrict__ ACCv, const float* __restrict__ HDR, int scIdx) {
  if ((*flag == 1) != F32) return;
  int b = blockIdx.x >> 7, w = blockIdx.x & 127;
  __shared__ float qcol[8][128], kcol[8][128];
  __shared__ float Vs[64 * 129];
  __shared__ float As[32 * 129];
  __shared__ float Ml[128], Li[128];
  int tid = threadIdx.x;
  for (int i = tid; i < 1024; i += 128) {
    int c = i >> 7, j = i & 127;
    size_t idx = ((size_t)(b * 8 + c)) * NP + (size_t)w * 128 + j;
    qcol[c][j] = bf2f(QT[idx]);
    kcol[c][j] = bf2f(KT[idx]);
  }
  for (int i = tid; i < 8192; i += 128) {
    int c = i >> 7, j = i & 127;
    Vs[c * 129 + j] = bf2f(VT[((size_t)(b * 64 + c)) * NP + (size_t)w * 128 + j]);
  }
  Ml[tid] = M[(size_t)b * NP + (size_t)tid * 128 + w];
  Li[tid] = LI[(size_t)b * NP + (size_t)tid * 128 + w];
  float sc = HDR[scIdx];
  int ig = tid & 7, cg = tid >> 3, c0 = cg * 4;
  int ar = tid >> 2, av = tid & 3;
  size_t outBase = (size_t)(b * 64) * NP + w;
  for (int chunk = 0; chunk < 4; ++chunk) {
    __syncthreads();
    {
      int hh = chunk * 32 + ar;
      float mv = Ml[hh], li = Li[hh];
      for (int k = 0; k < 32; ++k) {
        int g = av * 32 + k;
        float s = 0.f;
#pragma unroll
        for (int c = 0; c < 8; ++c) s = fmaf(qcol[c][hh], kcol[c][g], s);
        As[ar * 129 + g] = (g == hh) ? 0.f : __expf(s - mv) * li;
      }
    }
    __syncthreads();
    float acc[4][4];
#pragma unroll
    for (int ii = 0; ii < 4; ++ii)
#pragma unroll
      for (int cc = 0; cc < 4; ++cc) acc[ii][cc] = 0.f;
    for (int j = 0; j < 128; ++j) {
      float a[4], vv[4];
#pragma unroll
      for (int ii = 0; ii < 4; ++ii) a[ii] = As[(ig * 4 + ii) * 129 + j];
#pragma unroll
      for (int cc = 0; cc < 4; ++cc) vv[cc] = Vs[(c0 + cc) * 129 + j];
#pragma unroll
      for (int ii = 0; ii < 4; ++ii)
#pragma unroll
        for (int cc = 0; cc < 4; ++cc) acc[ii][cc] = fmaf(a[ii], vv[cc], acc[ii][cc]);
    }
    int i0 = chunk * 32 + ig * 4;
#pragma unroll
    for (int ii = 0; ii < 4; ++ii)
#pragma unroll
      for (int cc = 0; cc < 4; ++cc) {
        size_t oidx = outBase + (size_t)(c0 + cc) * NP + (size_t)(i0 + ii) * 128;
        float val = sc * acc[ii][cc];
        if (F32) {
          float* A = (float*)ACCv;
          A[oidx] += val;
        } else {
          bf16* A = (bf16*)ACCv;
          A[oidx] = f2bf(bf2f(A[oidx]) + val);
        }
      }
  }
}

// ---------------------------------------------------------------------------
// K9: partial Gram of y=BN(Y) applied at staging (internal)
// ---------------------------------------------------------------------------
__global__ __launch_bounds__(256) void k_gram(const bf16* __restrict__ Y,
                                              const float* __restrict__ SCALE,
                                              const float* __restrict__ SHIFT,
                                              float* __restrict__ GP) {
  int b = blockIdx.x >> 5, ch = blockIdx.x & 31;
  int tid = threadIdx.x;
  __shared__ float fs[64 * 129];
  int cg = tid >> 4, dg = tid & 15;
  float acc[4][4];
#pragma unroll
  for (int i = 0; i < 4; ++i)
#pragma unroll
    for (int jx = 0; jx < 4; ++jx) acc[i][jx] = 0.f;
  const bf16* yb = Y + (size_t)b * 64 * NP + ch * 512;
  for (int t = 0; t < 4; ++t) {
    __syncthreads();
    for (int idx = tid; idx < 8192; idx += 256) {
      int c = idx >> 7, j = idx & 127;
      float v = fmaf(bf2f(yb[(size_t)c * NP + t * 128 + j]), SCALE[c], SHIFT[c]);
      fs[c * 129 + j] = fmaxf(v, 0.f);
    }
    __syncthreads();
    for (int j = 0; j < 128; ++j) {
      float a[4], d[4];
#pragma unroll
      for (int i = 0; i < 4; ++i) a[i] = fs[(cg * 4 + i) * 129 + j];
#pragma unroll
      for (int i = 0; i < 4; ++i) d[i] = fs[(dg * 4 + i) * 129 + j];
#pragma unroll
      for (int i = 0; i < 4; ++i)
#pragma unroll
        for (int jx = 0; jx < 4; ++jx) acc[i][jx] = fmaf(a[i], d[jx], acc[i][jx]);
    }
  }
  float* gp = GP + ((size_t)b * 32 + ch) * 4096;
#pragma unroll
  for (int i = 0; i < 4; ++i)
#pragma unroll
    for (int jx = 0; jx < 4; ++jx)
      gp[(cg * 4 + i) * 64 + dg * 4 + jx] = acc[i][jx];
}

// K10: reduce Gram partials; row softmax of (max-E)
__global__ __launch_bounds__(256) void k_gram_reduce(const float* __restrict__ GP,
                                                     float* __restrict__ CATT) {
  int b = blockIdx.x, tid = threadIdx.x;
  __shared__ float Es[4096];
  for (int e = tid; e < 4096; e += 256) {
    float s = 0.f;
    for (int k = 0; k < 32; ++k) s += GP[((size_t)b * 32 + k) * 4096 + e];
    Es[e] = s;
  }
  __syncthreads();
  int wv = tid >> 6, ln = tid & 63;
  for (int r = wv; r < 64; r += 4) {
    float v = Es[r * 64 + ln];
    float mn = v;
    for (int off = 32; off; off >>= 1) mn = fminf(mn, __shfl_xor(mn, off, 64));
    float e = __expf(mn - v);
    float s = e;
    for (int off = 32; off; off >>= 1) s += __shfl_xor(s, off, 64);
    CATT[((size_t)b * 64 + r) * 64 + ln] = e / s;
  }
}

// ---------------------------------------------------------------------------
// K11: out = (2+pg)*x + pg2*y + ACC + cg*(catt@y). In-place on d_out.
// ---------------------------------------------------------------------------
template <bool F32>
__global__ __launch_bounds__(256) void k_final(
    const int* __restrict__ flag, const void* __restrict__ x,
    const bf16* __restrict__ Y, const float* __restrict__ SCALE,
    const float* __restrict__ SHIFT, const float* __restrict__ CATT,
    const float* __restrict__ HDR, void* __restrict__ OUTv) {
  if ((*flag == 1) != F32) return;
  __shared__ float attS[64 * 65], Ys[64 * 65];
  int tid = threadIdx.x;
  int b = blockIdx.x >> 8, tile = blockIdx.x & 255;
  int n0 = tile * 64;
  for (int i = tid; i < 4096; i += 256)
    attS[(i >> 6) * 65 + (i & 63)] = CATT[(size_t)b * 4096 + i];
  for (int i = tid; i < 4096; i += 256) {
    int d = i >> 6, px = i & 63;
    float v = fmaf(bf2f(Y[(size_t)(b * 64 + d) * NP + n0 + px]), SCALE[d], SHIFT[d]);
    Ys[d * 65 + px] = fmaxf(v, 0.f);
  }
  __syncthreads();
  int cg = tid >> 4, pgx = tid & 15;
  int c0 = cg * 4, p0 = pgx * 4;
  float acc[4][4];
#pragma unroll
  for (int i = 0; i < 4; ++i)
#pragma unroll
    for (int j = 0; j < 4; ++j) acc[i][j] = 0.f;
  for (int d = 0; d < 64; ++d) {
    float a[4], yv[4];
#pragma unroll
    for (int i = 0; i < 4; ++i) a[i] = attS[(c0 + i) * 65 + d];
#pragma unroll
    for (int j = 0; j < 4; ++j) yv[j] = Ys[d * 65 + p0 + j];
#pragma unroll
    for (int i = 0; i < 4; ++i)
#pragma unroll
      for (int j = 0; j < 4; ++j) acc[i][j] = fmaf(a[i], yv[j], acc[i][j]);
  }
  float c2pg = HDR[3], fpg2 = HDR[4], fcg = HDR[5];
#pragma unroll
  for (int i = 0; i < 4; ++i) {
    size_t base = (size_t)(b * 64 + c0 + i) * NP + n0 + p0;
#pragma unroll
    for (int j = 0; j < 4; ++j) {
      float xv = ldin<F32>(x, base + j);
      float yv = Ys[(c0 + i) * 65 + p0 + j];
      if (F32) {
        float* O = (float*)OUTv;
        O[base + j] = c2pg * xv + fpg2 * yv + O[base + j] + fcg * acc[i][j];
      } else {
        bf16* O = (bf16*)OUTv;
        O[base + j] =
            f2bf(c2pg * xv + fpg2 * yv + bf2f(O[base + j]) + fcg * acc[i][j]);
      }
    }
  }
}

// ---------------------------------------------------------------------------
extern "C" void kernel_launch(void* const* d_in, const int* in_sizes, int n_in,
                              void* d_out, int out_size, void* d_ws, size_t ws_size,
                              hipStream_t stream) {
  const void* x = d_in[0];
  const void* fbp = d_in[1];

  // Workspace: 29,888,512 bytes total (round-3-proven extent).
  char* base = (char*)d_ws;
  int* FLAG = (int*)base;          // word 0
  float* HDR = (float*)base;       // words 1..5 scalars
  float* MU = HDR + 16;
  float* RSTD = MU + 64;
  float* SCALE = RSTD + 64;
  float* SHIFT = SCALE + 64;
  char* p = base + 4096;
  bf16* Y = (bf16*)p;   p += 8388608;
  bf16* Q = (bf16*)p;   p += 1048576;
  bf16* K = (bf16*)p;   p += 1048576;
  bf16* QT = (bf16*)p;  p += 1048576;
  bf16* KT = (bf16*)p;  p += 1048576;
  bf16* V = (bf16*)p;   p += 8388608;
  bf16* VT = (bf16*)p;  p += 8388608;
  float* MW = (float*)p; p += 262144;   // joint M after combine
  float* LW = (float*)p; p += 262144;   // joint 1/L after combine
  void* ACC = d_out;                    // native output dtype in both worlds
  float* GP = (float*)Q;     // reuses Q/K after module loop
  float* CATT = (float*)QT;  // reuses QT

  k_detect<<<1, 256, 0, stream>>>(x, FLAG);
  k_pool_conv<false><<<1024, 256, 0, stream>>>(FLAG, fbp, d_in[2], d_in[3], Y);
  k_pool_conv<true><<<1024, 256, 0, stream>>>(FLAG, fbp, d_in[2], d_in[3], Y);
  k_stats<<<64, 256, 0, stream>>>(Y, MU, RSTD);
  k_bnscale<false><<<1, 64, 0, stream>>>(FLAG, d_in[4], d_in[5], MU, RSTD,
                                         SCALE, SHIFT, d_in[12], d_in[19],
                                         d_in[20], d_in[21], d_in[22], HDR);
  k_bnscale<true><<<1, 64, 0, stream>>>(FLAG, d_in[4], d_in[5], MU, RSTD,
                                        SCALE, SHIFT, d_in[12], d_in[19],
                                        d_in[20], d_in[21], d_in[22], HDR);

  for (int m = 0; m < 2; ++m) {
    const void *qw, *qb, *kw, *kb, *vw, *vb;
    if (m == 0) {
      qw = d_in[6]; qb = d_in[7]; kw = d_in[8]; kb = d_in[9];
      vw = d_in[10]; vb = d_in[11];
    } else {
      qw = d_in[13]; qb = d_in[14]; kw = d_in[15]; kb = d_in[16];
      vw = d_in[17]; vb = d_in[18];
    }
    if (m == 0) {
      k_conv80<false, false><<<512, 256, 0, stream>>>(
          FLAG, x, SCALE, SHIFT, qw, qb, kw, kb, vw, vb, Q, K, V);
      k_conv80<true, false><<<512, 256, 0, stream>>>(
          FLAG, x, SCALE, SHIFT, qw, qb, kw, kb, vw, vb, Q, K, V);
    } else {
      k_conv80<false, true><<<512, 256, 0, stream>>>(
          FLAG, Y, SCALE, SHIFT, qw, qb, kw, kb, vw, vb, Q, K, V);
      k_conv80<true, true><<<512, 256, 0, stream>>>(
          FLAG, Y, SCALE, SHIFT, qw, qb, kw, kb, vw, vb, Q, K, V);
    }
    k_transpose<<<512, 256, 0, stream>>>((const u16*)Q, (u16*)QT);
    k_transpose<<<512, 256, 0, stream>>>((const u16*)K, (u16*)KT);
    k_transpose<<<4096, 256, 0, stream>>>((const u16*)V, (u16*)VT);
    k_ew_stats<<<512, 256, 0, stream>>>(Q, K, MW, LW);
    k_eh_combine<<<512, 256, 0, stream>>>(QT, KT, MW, LW);
    k_av_w<false><<<512, 128, 0, stream>>>(FLAG, Q, K, V, MW, LW, ACC, HDR,
                                           1 + m, m);
    k_av_w<true><<<512, 128, 0, stream>>>(FLAG, Q, K, V, MW, LW, ACC, HDR,
                                          1 + m, m);
    k_av_h<false><<<512, 128, 0, stream>>>(FLAG, QT, KT, VT, MW, LW, ACC, HDR,
                                           1 + m);
    k_av_h<true><<<512, 128, 0, stream>>>(FLAG, QT, KT, VT, MW, LW, ACC, HDR,
                                          1 + m);
  }

  k_gram<<<128, 256, 0, stream>>>(Y, SCALE, SHIFT, GP);
  k_gram_reduce<<<4, 256, 0, stream>>>(GP, CATT);
  k_final<false><<<1024, 256, 0, stream>>>(FLAG, x, Y, SCALE, SHIFT, CATT, HDR,
                                           d_out);
  k_final<true><<<1024, 256, 0, stream>>>(FLAG, x, Y, SCALE, SHIFT, CATT, HDR,
                                          d_out);
}

// Round 7
// 590.835 us; speedup vs baseline: 1.7794x; 1.3043x over previous
//
#include <hip/hip_runtime.h>
#include <hip/hip_bf16.h>

#define NP 16384   // H*W
#define NB 4

typedef __hip_bfloat16 bf16;
typedef unsigned short u16;
__device__ __forceinline__ float bf2f(const bf16 v) { return __bfloat162float(v); }
__device__ __forceinline__ bf16 f2bf(float v) { return __float2bfloat16(v); }

// Inputs/outputs are fp32 (reference dtype; established R3/R6 vs R4/R5).
// Internal tensors bf16; accumulation fp32.

// ---------------------------------------------------------------------------
// K1: maxpool2x2(fb fp32) -> conv1x1+bias -> Y raw (pre-BN, bf16). 64x64 tile.
// ---------------------------------------------------------------------------
__global__ __launch_bounds__(256) void k_pool_conv(
    const float* __restrict__ fb, const float* __restrict__ wconv,
    const float* __restrict__ bconv, bf16* __restrict__ Y) {
  __shared__ float wS[4096], bS[64], Xs[4096];
  int tid = threadIdx.x;
  int b = blockIdx.x >> 8, tile = blockIdx.x & 255;
  int n0 = tile * 64;
  for (int i = tid; i < 4096; i += 256) wS[i] = wconv[i];
  if (tid < 64) bS[tid] = bconv[tid];
  for (int i = tid; i < 4096; i += 256) {
    int c = i >> 6, px = i & 63;
    int n = n0 + px, h = n >> 7, w = n & 127;
    size_t fbase = ((size_t)((b * 64 + c) * 256 + 2 * h)) * 256 + 2 * w;
    float v0 = fb[fbase], v1 = fb[fbase + 1];
    float v2 = fb[fbase + 256], v3 = fb[fbase + 257];
    Xs[i] = fmaxf(fmaxf(v0, v1), fmaxf(v2, v3));
  }
  __syncthreads();
  int ty = tid >> 4, tx = tid & 15;
  float acc[4][4];
#pragma unroll
  for (int i = 0; i < 4; ++i) {
    float bv = bS[ty + 16 * i];
#pragma unroll
    for (int j = 0; j < 4; ++j) acc[i][j] = bv;
  }
  for (int c = 0; c < 64; ++c) {
    float xv[4], wv[4];
#pragma unroll
    for (int j = 0; j < 4; ++j) xv[j] = Xs[c * 64 + tx * 4 + j];
#pragma unroll
    for (int i = 0; i < 4; ++i) wv[i] = wS[(ty + 16 * i) * 64 + c];
#pragma unroll
    for (int i = 0; i < 4; ++i)
#pragma unroll
      for (int j = 0; j < 4; ++j) acc[i][j] = fmaf(wv[i], xv[j], acc[i][j]);
  }
#pragma unroll
  for (int i = 0; i < 4; ++i) {
    int ch = ty + 16 * i;
    bf16* yb = Y + (size_t)(b * 64 + ch) * NP + n0 + tx * 4;
#pragma unroll
    for (int j = 0; j < 4; ++j) yb[j] = f2bf(acc[i][j]);
  }
}

// ---------------------------------------------------------------------------
// K2: per-channel mean/rstd over (B,H,W) from raw Y
// ---------------------------------------------------------------------------
__global__ __launch_bounds__(256) void k_stats(const bf16* __restrict__ Y,
                                               float* __restrict__ MU,
                                               float* __restrict__ RSTD) {
  int o = blockIdx.x, tid = threadIdx.x;
  float s = 0.f, ss = 0.f;
  for (int b = 0; b < NB; ++b) {
    const bf16* p = Y + ((size_t)(b * 64 + o)) * NP;
    for (int i = tid; i < NP; i += 256) {
      float v = bf2f(p[i]);
      s += v; ss = fmaf(v, v, ss);
    }
  }
  for (int off = 32; off > 0; off >>= 1) {
    s += __shfl_down(s, off, 64);
    ss += __shfl_down(ss, off, 64);
  }
  __shared__ float sh[8];
  int wv = tid >> 6, ln = tid & 63;
  if (ln == 0) { sh[wv] = s; sh[4 + wv] = ss; }
  __syncthreads();
  if (tid == 0) {
    float S = sh[0] + sh[1] + sh[2] + sh[3];
    float SS = sh[4] + sh[5] + sh[6] + sh[7];
    const float inv = 1.0f / (NB * NP);
    float mu = S * inv;
    float var = SS * inv - mu * mu;
    MU[o] = mu;
    RSTD[o] = rsqrtf(var + 1e-5f);
  }
}

// K2b: BN scale/shift + scalar header (fp32 params)
__global__ __launch_bounds__(64) void k_bnscale(
    const float* __restrict__ bng, const float* __restrict__ bnb,
    const float* __restrict__ MU, const float* __restrict__ RSTD,
    float* __restrict__ SCALE, float* __restrict__ SHIFT,
    const float* xg, const float* fg, const float* pg, const float* pg2,
    const float* cg, float* __restrict__ HDR) {
  int o = threadIdx.x;
  float sc = RSTD[o] * bng[o];
  SCALE[o] = sc;
  SHIFT[o] = bnb[o] - MU[o] * sc;
  if (o == 0) {
    float vpg = pg[0];
    HDR[1] = vpg * xg[0];
    HDR[2] = pg2[0] * fg[0];
    HDR[3] = 2.0f + vpg;
    HDR[4] = pg2[0];
    HDR[5] = cg[0];
  }
}

// ---------------------------------------------------------------------------
// K4: fused q|k|v conv1x1: 80 out-ch x 128 px, 5x8 thread tile.
// BN=false: input external fp32 x. BN=true: input internal bf16 Y (BN+ReLU
// at staging). Weights always external fp32.
// ---------------------------------------------------------------------------
template <bool BN>
__global__ __launch_bounds__(256) void k_conv80(
    const void* __restrict__ inp, const float* __restrict__ SCALE,
    const float* __restrict__ SHIFT,
    const float* __restrict__ qw, const float* __restrict__ qb,
    const float* __restrict__ kw, const float* __restrict__ kb,
    const float* __restrict__ vw, const float* __restrict__ vb,
    bf16* __restrict__ Q, bf16* __restrict__ K, bf16* __restrict__ V) {
  __shared__ float wS[5120], bS[80], Xs[8192];
  int tid = threadIdx.x;
  int b = blockIdx.x >> 7, tile = blockIdx.x & 127;
  int n0 = tile * 128;
  for (int i = tid; i < 512; i += 256) { wS[i] = qw[i]; wS[512 + i] = kw[i]; }
  for (int i = tid; i < 4096; i += 256) wS[1024 + i] = vw[i];
  if (tid < 8) { bS[tid] = qb[tid]; bS[8 + tid] = kb[tid]; }
  if (tid < 64) bS[16 + tid] = vb[tid];
  for (int i = tid; i < 8192; i += 256) {
    int c = i >> 7, px = i & 127;
    size_t idx = (size_t)(b * 64 + c) * NP + n0 + px;
    float v;
    if (BN) {
      v = bf2f(((const bf16*)inp)[idx]);
      v = fmaf(v, SCALE[c], SHIFT[c]);
      v = fmaxf(v, 0.f);
    } else {
      v = ((const float*)inp)[idx];
    }
    Xs[i] = v;
  }
  __syncthreads();
  int ty = tid >> 4, tx = tid & 15;
  float acc[5][8];
#pragma unroll
  for (int i = 0; i < 5; ++i) {
    float bv = bS[ty + 16 * i];
#pragma unroll
    for (int j = 0; j < 8; ++j) acc[i][j] = bv;
  }
  for (int c = 0; c < 64; ++c) {
    float xv[8], wv[5];
#pragma unroll
    for (int j = 0; j < 8; ++j) xv[j] = Xs[c * 128 + tx + 16 * j];
#pragma unroll
    for (int i = 0; i < 5; ++i) wv[i] = wS[(ty + 16 * i) * 64 + c];
#pragma unroll
    for (int i = 0; i < 5; ++i)
#pragma unroll
      for (int j = 0; j < 8; ++j) acc[i][j] = fmaf(wv[i], xv[j], acc[i][j]);
  }
#pragma unroll
  for (int i = 0; i < 5; ++i) {
    int ch = ty + 16 * i;
    bf16* dst;
    size_t base;
    if (ch < 8) { dst = Q; base = (size_t)(b * 8 + ch) * NP; }
    else if (ch < 16) { dst = K; base = (size_t)(b * 8 + ch - 8) * NP; }
    else { dst = V; base = (size_t)(b * 64 + ch - 16) * NP; }
#pragma unroll
    for (int j = 0; j < 8; ++j) dst[base + n0 + tx + 16 * j] = f2bf(acc[i][j]);
  }
}

// ---------------------------------------------------------------------------
// K5: 128x128 bf16 plane transpose
// ---------------------------------------------------------------------------
__global__ __launch_bounds__(256) void k_transpose(const u16* __restrict__ in,
                                                   u16* __restrict__ out) {
  int tileId = blockIdx.x & 15;
  int plane = blockIdx.x >> 4;
  int th = tileId >> 2, tw = tileId & 3;
  __shared__ u16 t[32][33];
  int lx = threadIdx.x & 31, ly = threadIdx.x >> 5;
  const u16* ip = in + (size_t)plane * NP;
  for (int i = 0; i < 32; i += 8)
    t[ly + i][lx] = ip[(size_t)(th * 32 + ly + i) * 128 + tw * 32 + lx];
  __syncthreads();
  u16* op = out + (size_t)plane * NP;
  for (int i = 0; i < 32; i += 8)
    op[(size_t)(tw * 32 + ly + i) * 128 + th * 32 + lx] = t[lx][ly + i];
}

// ---------------------------------------------------------------------------
// K6a: e_w per-row max/sumexp -> raw stats into MW/LW
// ---------------------------------------------------------------------------
__global__ __launch_bounds__(256) void k_ew_stats(
    const bf16* __restrict__ Q, const bf16* __restrict__ K,
    float* __restrict__ MW, float* __restrict__ LW) {
  int b = blockIdx.x >> 7, h = blockIdx.x & 127;
  __shared__ float qs[1024], ks[1024], red[256];
  int tid = threadIdx.x;
  for (int i = tid; i < 1024; i += 256) {
    int c = i >> 7, j = i & 127;
    size_t idx = (size_t)(b * 8 + c) * NP + (size_t)h * 128 + j;
    qs[i] = bf2f(Q[idx]);
    ks[i] = bf2f(K[idx]);
  }
  __syncthreads();
  int w = tid & 127, half = tid >> 7;
  float qr[8];
#pragma unroll
  for (int c = 0; c < 8; ++c) qr[c] = qs[c * 128 + w];
  float m = -3.0e38f;
  for (int v0 = 0; v0 < 64; ++v0) {
    int v = half * 64 + v0;
    float s = 0.f;
#pragma unroll
    for (int c = 0; c < 8; ++c) s = fmaf(qr[c], ks[c * 128 + v], s);
    m = fmaxf(m, s);
  }
  red[tid] = m;
  __syncthreads();
  float mj = fmaxf(red[w], red[128 + w]);
  __syncthreads();
  float l = 0.f;
  for (int v0 = 0; v0 < 64; ++v0) {
    int v = half * 64 + v0;
    float s = 0.f;
#pragma unroll
    for (int c = 0; c < 8; ++c) s = fmaf(qr[c], ks[c * 128 + v], s);
    l += __expf(s - mj);
  }
  red[tid] = l;
  __syncthreads();
  if (half == 0) {
    size_t o = (size_t)b * NP + (size_t)h * 128 + w;
    MW[o] = mj;
    LW[o] = red[w] + red[128 + w];
  }
}

// ---------------------------------------------------------------------------
// K6b: e_h per-row stats (diag masked) + in-place combine -> MW=M, LW=1/L
// ---------------------------------------------------------------------------
__global__ __launch_bounds__(256) void k_eh_combine(
    const bf16* __restrict__ QT, const bf16* __restrict__ KT,
    float* __restrict__ MW, float* __restrict__ LW) {
  int b = blockIdx.x >> 7, w = blockIdx.x & 127;
  __shared__ float qs[1024], ks[1024], red[256];
  int tid = threadIdx.x;
  for (int i = tid; i < 1024; i += 256) {
    int c = i >> 7, j = i & 127;
    size_t idx = (size_t)(b * 8 + c) * NP + (size_t)w * 128 + j;
    qs[i] = bf2f(QT[idx]);
    ks[i] = bf2f(KT[idx]);
  }
  __syncthreads();
  int h = tid & 127, half = tid >> 7;
  float qr[8];
#pragma unroll
  for (int c = 0; c < 8; ++c) qr[c] = qs[c * 128 + h];
  float m = -3.0e38f;
  for (int g0 = 0; g0 < 64; ++g0) {
    int g = half * 64 + g0;
    float s = 0.f;
#pragma unroll
    for (int c = 0; c < 8; ++c) s = fmaf(qr[c], ks[c * 128 + g], s);
    if (g == h) s = -1.0e30f;
    m = fmaxf(m, s);
  }
  red[tid] = m;
  __syncthreads();
  float mj = fmaxf(red[h], red[128 + h]);
  __syncthreads();
  float l = 0.f;
  for (int g0 = 0; g0 < 64; ++g0) {
    int g = half * 64 + g0;
    float s = 0.f;
#pragma unroll
    for (int c = 0; c < 8; ++c) s = fmaf(qr[c], ks[c * 128 + g], s);
    l += (g == h) ? 0.f : __expf(s - mj);
  }
  red[tid] = l;
  __syncthreads();
  if (half == 0) {
    size_t o = (size_t)b * NP + (size_t)h * 128 + w;
    float lh = red[h] + red[128 + h];
    float mw = MW[o], lw = LW[o];
    float mm = fmaxf(mw, mj);
    float ll = lw * __expf(mw - mm) + lh * __expf(mj - mm);
    MW[o] = mm;
    LW[o] = 1.0f / ll;
  }
}

// ---------------------------------------------------------------------------
// K7: out_w. Block (b,h). ACC (fp32 d_out) (+)= sc*out_w, contiguous writes.
// Score-write index remap v = av*8+(k&7)+(k>>3)*32: 2-way banks (free).
// ---------------------------------------------------------------------------
__global__ __launch_bounds__(128) void k_av_w(
    const bf16* __restrict__ Q, const bf16* __restrict__ K,
    const bf16* __restrict__ V, const float* __restrict__ M,
    const float* __restrict__ LI, float* __restrict__ ACC,
    const float* __restrict__ HDR, int scIdx, int accum) {
  int b = blockIdx.x >> 7, h = blockIdx.x & 127;
  __shared__ float qrow[8][128], krow[8][128];
  __shared__ float Vs[64 * 129];
  __shared__ float As[32 * 129];
  __shared__ float Ml[128], Li[128];
  int tid = threadIdx.x;
  for (int i = tid; i < 1024; i += 128) {
    int c = i >> 7, j = i & 127;
    size_t idx = ((size_t)(b * 8 + c)) * NP + (size_t)h * 128 + j;
    qrow[c][j] = bf2f(Q[idx]);
    krow[c][j] = bf2f(K[idx]);
  }
  for (int i = tid; i < 8192; i += 128) {
    int c = i >> 7, j = i & 127;
    Vs[c * 129 + j] = bf2f(V[((size_t)(b * 64 + c)) * NP + (size_t)h * 128 + j]);
  }
  Ml[tid] = M[(size_t)b * NP + (size_t)h * 128 + tid];
  Li[tid] = LI[(size_t)b * NP + (size_t)h * 128 + tid];
  float sc = HDR[scIdx];
  int ig = tid & 7, cg = tid >> 3, c0 = cg * 4;
  int ar = tid >> 2, av = tid & 3;
  float* accBase = ACC + (size_t)(b * 64) * NP + (size_t)h * 128;
  for (int chunk = 0; chunk < 4; ++chunk) {
    __syncthreads();
    {
      int w = chunk * 32 + ar;
      float mv = Ml[w], li = Li[w];
      for (int k = 0; k < 32; ++k) {
        int v = av * 8 + (k & 7) + (k >> 3) * 32;
        float s = 0.f;
#pragma unroll
        for (int c = 0; c < 8; ++c) s = fmaf(qrow[c][w], krow[c][v], s);
        As[ar * 129 + v] = __expf(s - mv) * li;
      }
    }
    __syncthreads();
    float acc[4][4];
#pragma unroll
    for (int ii = 0; ii < 4; ++ii)
#pragma unroll
      for (int cc = 0; cc < 4; ++cc) acc[ii][cc] = 0.f;
    for (int j = 0; j < 128; ++j) {
      float a[4], vv[4];
#pragma unroll
      for (int ii = 0; ii < 4; ++ii) a[ii] = As[(ig * 4 + ii) * 129 + j];
#pragma unroll
      for (int cc = 0; cc < 4; ++cc) vv[cc] = Vs[(c0 + cc) * 129 + j];
#pragma unroll
      for (int ii = 0; ii < 4; ++ii)
#pragma unroll
        for (int cc = 0; cc < 4; ++cc) acc[ii][cc] = fmaf(a[ii], vv[cc], acc[ii][cc]);
    }
    int i0 = chunk * 32 + ig * 4;
#pragma unroll
    for (int ii = 0; ii < 4; ++ii)
#pragma unroll
      for (int cc = 0; cc < 4; ++cc) {
        size_t oidx = (size_t)(c0 + cc) * NP + (size_t)(i0 + ii);
        float val = sc * acc[ii][cc];
        accBase[oidx] = (accum ? accBase[oidx] : 0.f) + val;
      }
  }
}

// ---------------------------------------------------------------------------
// K8: out_h. Block (b,w). Writes OHT[b][c][w][h] (natural layout, bf16,
// contiguous, no RMW). Diag masked. sc applied later in k_merge.
// ---------------------------------------------------------------------------
__global__ __launch_bounds__(128) void k_av_h(
    const bf16* __restrict__ QT, const bf16* __restrict__ KT,
    const bf16* __restrict__ VT, const float* __restrict__ M,
    const float* __restrict__ LI, bf16* __restrict__ OHT) {
  int b = blockIdx.x >> 7, w = blockIdx.x & 127;
  __shared__ float qcol[8][128], kcol[8][128];
  __shared__ float Vs[64 * 129];
  __shared__ float As[32 * 129];
  __shared__ float Ml[128], Li[128];
  int tid = threadIdx.x;
  for (int i = tid; i < 1024; i += 128) {
    int c = i >> 7, j = i & 127;
    size_t idx = ((size_t)(b * 8 + c)) * NP + (size_t)w * 128 + j;
    qcol[c][j] = bf2f(QT[idx]);
    kcol[c][j] = bf2f(KT[idx]);
  }
  for (int i = tid; i < 8192; i += 128) {
    int c = i >> 7, j = i & 127;
    Vs[c * 129 + j] = bf2f(VT[((size_t)(b * 64 + c)) * NP + (size_t)w * 128 + j]);
  }
  Ml[tid] = M[(size_t)b * NP + (size_t)tid * 128 + w];
  Li[tid] = LI[(size_t)b * NP + (size_t)tid * 128 + w];
  int ig = tid & 7, cg = tid >> 3, c0 = cg * 4;
  int ar = tid >> 2, av = tid & 3;
  bf16* outBase = OHT + (size_t)(b * 64) * NP + (size_t)w * 128;
  for (int chunk = 0; chunk < 4; ++chunk) {
    __syncthreads();
    {
      int hh = chunk * 32 + ar;
      float mv = Ml[hh], li = Li[hh];
      for (int k = 0; k < 32; ++k) {
        int g = av * 8 + (k & 7) + (k >> 3) * 32;
        float s = 0.f;
#pragma unroll
        for (int c = 0; c < 8; ++c) s = fmaf(qcol[c][hh], kcol[c][g], s);
        As[ar * 129 + g] = (g == hh) ? 0.f : __expf(s - mv) * li;
      }
    }
    __syncthreads();
    float acc[4][4];
#pragma unroll
    for (int ii = 0; ii < 4; ++ii)
#pragma unroll
      for (int cc = 0; cc < 4; ++cc) acc[ii][cc] = 0.f;
    for (int j = 0; j < 128; ++j) {
      float a[4], vv[4];
#pragma unroll
      for (int ii = 0; ii < 4; ++ii) a[ii] = As[(ig * 4 + ii) * 129 + j];
#pragma unroll
      for (int cc = 0; cc < 4; ++cc) vv[cc] = Vs[(c0 + cc) * 129 + j];
#pragma unroll
      for (int ii = 0; ii < 4; ++ii)
#pragma unroll
        for (int cc = 0; cc < 4; ++cc) acc[ii][cc] = fmaf(a[ii], vv[cc], acc[ii][cc]);
    }
    int i0 = chunk * 32 + ig * 4;
#pragma unroll
    for (int ii = 0; ii < 4; ++ii)
#pragma unroll
      for (int cc = 0; cc < 4; ++cc) {
        size_t oidx = (size_t)(c0 + cc) * NP + (size_t)(i0 + ii);
        outBase[oidx] = f2bf(acc[ii][cc]);
      }
  }
}

// ---------------------------------------------------------------------------
// K8b: transpose-add: ACC[b][c][h][w] += sc * OHT[b][c][w][h]. LDS 32x32.
// Coalesced both sides. grid = 256 planes * 16 tiles.
// ---------------------------------------------------------------------------
__global__ __launch_bounds__(256) void k_merge(const bf16* __restrict__ OHT,
                                               float* __restrict__ ACC,
                                               const float* __restrict__ HDR,
                                               int scIdx) {
  int tileId = blockIdx.x & 15;
  int plane = blockIdx.x >> 4;
  int th = tileId >> 2, tw = tileId & 3;
  __shared__ float t[32][33];
  int lx = threadIdx.x & 31, ly = threadIdx.x >> 5;
  const bf16* ip = OHT + (size_t)plane * NP;
  for (int i = 0; i < 32; i += 8)
    t[ly + i][lx] = bf2f(ip[(size_t)(th * 32 + ly + i) * 128 + tw * 32 + lx]);
  __syncthreads();
  float sc = HDR[scIdx];
  float* op = ACC + (size_t)plane * NP;
  for (int i = 0; i < 32; i += 8) {
    int h = tw * 32 + ly + i, w = th * 32 + lx;
    op[(size_t)h * 128 + w] += sc * t[lx][ly + i];
  }
}

// ---------------------------------------------------------------------------
// K9: partial Gram of y=BN(Y) applied at staging
// ---------------------------------------------------------------------------
__global__ __launch_bounds__(256) void k_gram(const bf16* __restrict__ Y,
                                              const float* __restrict__ SCALE,
                                              const float* __restrict__ SHIFT,
                                              float* __restrict__ GP) {
  int b = blockIdx.x >> 5, ch = blockIdx.x & 31;
  int tid = threadIdx.x;
  __shared__ float fs[64 * 129];
  int cg = tid >> 4, dg = tid & 15;
  float acc[4][4];
#pragma unroll
  for (int i = 0; i < 4; ++i)
#pragma unroll
    for (int jx = 0; jx < 4; ++jx) acc[i][jx] = 0.f;
  const bf16* yb = Y + (size_t)b * 64 * NP + ch * 512;
  for (int t = 0; t < 4; ++t) {
    __syncthreads();
    for (int idx = tid; idx < 8192; idx += 256) {
      int c = idx >> 7, j = idx & 127;
      float v = fmaf(bf2f(yb[(size_t)c * NP + t * 128 + j]), SCALE[c], SHIFT[c]);
      fs[c * 129 + j] = fmaxf(v, 0.f);
    }
    __syncthreads();
    for (int j = 0; j < 128; ++j) {
      float a[4], d[4];
#pragma unroll
      for (int i = 0; i < 4; ++i) a[i] = fs[(cg * 4 + i) * 129 + j];
#pragma unroll
      for (int i = 0; i < 4; ++i) d[i] = fs[(dg * 4 + i) * 129 + j];
#pragma unroll
      for (int i = 0; i < 4; ++i)
#pragma unroll
        for (int jx = 0; jx < 4; ++jx) acc[i][jx] = fmaf(a[i], d[jx], acc[i][jx]);
    }
  }
  float* gp = GP + ((size_t)b * 32 + ch) * 4096;
#pragma unroll
  for (int i = 0; i < 4; ++i)
#pragma unroll
    for (int jx = 0; jx < 4; ++jx)
      gp[(cg * 4 + i) * 64 + dg * 4 + jx] = acc[i][jx];
}

// K10: reduce Gram partials; row softmax of (max-E)
__global__ __launch_bounds__(256) void k_gram_reduce(const float* __restrict__ GP,
                                                     float* __restrict__ CATT) {
  int b = blockIdx.x, tid = threadIdx.x;
  __shared__ float Es[4096];
  for (int e = tid; e < 4096; e += 256) {
    float s = 0.f;
    for (int k = 0; k < 32; ++k) s += GP[((size_t)b * 32 + k) * 4096 + e];
    Es[e] = s;
  }
  __syncthreads();
  int wv = tid >> 6, ln = tid & 63;
  for (int r = wv; r < 64; r += 4) {
    float v = Es[r * 64 + ln];
    float mn = v;
    for (int off = 32; off; off >>= 1) mn = fminf(mn, __shfl_xor(mn, off, 64));
    float e = __expf(mn - v);
    float s = e;
    for (int off = 32; off; off >>= 1) s += __shfl_xor(s, off, 64);
    CATT[((size_t)b * 64 + r) * 64 + ln] = e / s;
  }
}

// ---------------------------------------------------------------------------
// K11: out = (2+pg)*x + pg2*y + ACC + cg*(catt@y). In-place fp32 on d_out.
// ---------------------------------------------------------------------------
__global__ __launch_bounds__(256) void k_final(
    const float* __restrict__ x, const bf16* __restrict__ Y,
    const float* __restrict__ SCALE, const float* __restrict__ SHIFT,
    const float* __restrict__ CATT, const float* __restrict__ HDR,
    float* __restrict__ OUT) {
  __shared__ float attS[64 * 65], Ys[64 * 65];
  int tid = threadIdx.x;
  int b = blockIdx.x >> 8, tile = blockIdx.x & 255;
  int n0 = tile * 64;
  for (int i = tid; i < 4096; i += 256)
    attS[(i >> 6) * 65 + (i & 63)] = CATT[(size_t)b * 4096 + i];
  for (int i = tid; i < 4096; i += 256) {
    int d = i >> 6, px = i & 63;
    float v = fmaf(bf2f(Y[(size_t)(b * 64 + d) * NP + n0 + px]), SCALE[d], SHIFT[d]);
    Ys[d * 65 + px] = fmaxf(v, 0.f);
  }
  __syncthreads();
  int cg = tid >> 4, pgx = tid & 15;
  int c0 = cg * 4, p0 = pgx * 4;
  float acc[4][4];
#pragma unroll
  for (int i = 0; i < 4; ++i)
#pragma unroll
    for (int j = 0; j < 4; ++j) acc[i][j] = 0.f;
  for (int d = 0; d < 64; ++d) {
    float a[4], yv[4];
#pragma unroll
    for (int i = 0; i < 4; ++i) a[i] = attS[(c0 + i) * 65 + d];
#pragma unroll
    for (int j = 0; j < 4; ++j) yv[j] = Ys[d * 65 + p0 + j];
#pragma unroll
    for (int i = 0; i < 4; ++i)
#pragma unroll
      for (int j = 0; j < 4; ++j) acc[i][j] = fmaf(a[i], yv[j], acc[i][j]);
  }
  float c2pg = HDR[3], fpg2 = HDR[4], fcg = HDR[5];
#pragma unroll
  for (int i = 0; i < 4; ++i) {
    size_t base = (size_t)(b * 64 + c0 + i) * NP + n0 + p0;
#pragma unroll
    for (int j = 0; j < 4; ++j) {
      float yv = Ys[(c0 + i) * 65 + p0 + j];
      OUT[base + j] =
          c2pg * x[base + j] + fpg2 * yv + OUT[base + j] + fcg * acc[i][j];
    }
  }
}

// ---------------------------------------------------------------------------
extern "C" void kernel_launch(void* const* d_in, const int* in_sizes, int n_in,
                              void* d_out, int out_size, void* d_ws, size_t ws_size,
                              hipStream_t stream) {
  const float* x = (const float*)d_in[0];
  const float* fbp = (const float*)d_in[1];

  // Workspace: 38,277,120 bytes total (== round-3 proven extent).
  char* base = (char*)d_ws;
  float* HDR = (float*)base;
  float* MU = HDR + 16;
  float* RSTD = MU + 64;
  float* SCALE = RSTD + 64;
  float* SHIFT = SCALE + 64;
  char* p = base + 4096;
  bf16* Y = (bf16*)p;   p += 8388608;
  bf16* Q = (bf16*)p;   p += 1048576;
  bf16* K = (bf16*)p;   p += 1048576;
  bf16* QT = (bf16*)p;  p += 1048576;
  bf16* KT = (bf16*)p;  p += 1048576;
  bf16* V = (bf16*)p;   p += 8388608;
  bf16* VT = (bf16*)p;  p += 8388608;
  float* MW = (float*)p; p += 262144;   // joint M after combine
  float* LW = (float*)p; p += 262144;   // joint 1/L after combine
  bf16* OHT = (bf16*)p;  p += 8388608;  // out_h in [b][c][w][h] layout
  float* ACC = (float*)d_out;           // fp32, 16 MB
  float* GP = (float*)Q;     // reuses Q/K after module loop
  float* CATT = (float*)QT;  // reuses QT

  k_pool_conv<<<1024, 256, 0, stream>>>(fbp, (const float*)d_in[2],
                                        (const float*)d_in[3], Y);
  k_stats<<<64, 256, 0, stream>>>(Y, MU, RSTD);
  k_bnscale<<<1, 64, 0, stream>>>((const float*)d_in[4], (const float*)d_in[5],
                                  MU, RSTD, SCALE, SHIFT,
                                  (const float*)d_in[12], (const float*)d_in[19],
                                  (const float*)d_in[20], (const float*)d_in[21],
                                  (const float*)d_in[22], HDR);

  for (int m = 0; m < 2; ++m) {
    const float *qw, *qb, *kw, *kb, *vw, *vb;
    if (m == 0) {
      qw = (const float*)d_in[6]; qb = (const float*)d_in[7];
      kw = (const float*)d_in[8]; kb = (const float*)d_in[9];
      vw = (const float*)d_in[10]; vb = (const float*)d_in[11];
    } else {
      qw = (const float*)d_in[13]; qb = (const float*)d_in[14];
      kw = (const float*)d_in[15]; kb = (const float*)d_in[16];
      vw = (const float*)d_in[17]; vb = (const float*)d_in[18];
    }
    if (m == 0)
      k_conv80<false><<<512, 256, 0, stream>>>(x, SCALE, SHIFT, qw, qb, kw, kb,
                                               vw, vb, Q, K, V);
    else
      k_conv80<true><<<512, 256, 0, stream>>>(Y, SCALE, SHIFT, qw, qb, kw, kb,
                                              vw, vb, Q, K, V);
    k_transpose<<<512, 256, 0, stream>>>((const u16*)Q, (u16*)QT);
    k_transpose<<<512, 256, 0, stream>>>((const u16*)K, (u16*)KT);
    k_transpose<<<4096, 256, 0, stream>>>((const u16*)V, (u16*)VT);
    k_ew_stats<<<512, 256, 0, stream>>>(Q, K, MW, LW);
    k_eh_combine<<<512, 256, 0, stream>>>(QT, KT, MW, LW);
    k_av_w<<<512, 128, 0, stream>>>(Q, K, V, MW, LW, ACC, HDR, 1 + m, m);
    k_av_h<<<512, 128, 0, stream>>>(QT, KT, VT, MW, LW, OHT);
    k_merge<<<4096, 256, 0, stream>>>(OHT, ACC, HDR, 1 + m);
  }

  k_gram<<<128, 256, 0, stream>>>(Y, SCALE, SHIFT, GP);
  k_gram_reduce<<<4, 256, 0, stream>>>(GP, CATT);
  k_final<<<1024, 256, 0, stream>>>(x, Y, SCALE, SHIFT, CATT, HDR,
                                    (float*)d_out);
}

// Round 8
// 567.445 us; speedup vs baseline: 1.8527x; 1.0412x over previous
//
#include <hip/hip_runtime.h>
#include <hip/hip_bf16.h>

#define NP 16384   // H*W
#define NB 4

typedef __hip_bfloat16 bf16;
typedef unsigned short u16;
typedef unsigned short us8 __attribute__((ext_vector_type(8)));
__device__ __forceinline__ float bf2f(const bf16 v) { return __bfloat162float(v); }
__device__ __forceinline__ bf16 f2bf(float v) { return __float2bfloat16(v); }
__device__ __forceinline__ float bfu(u16 h) {
  return __uint_as_float(((unsigned)h) << 16);
}
__device__ __forceinline__ u16 fbu(float v) {
  bf16 b = f2bf(v);
  return *(u16*)&b;
}

// Inputs/outputs fp32 (reference dtype). Internal tensors bf16, math fp32.

// ---------------------------------------------------------------------------
// K1: maxpool2x2(fb fp32) -> conv1x1+bias -> Y raw (pre-BN, bf16). 64x64 tile.
// wS stride 65 (bank-conflict-free weight reads); float2 pool loads.
// ---------------------------------------------------------------------------
__global__ __launch_bounds__(256) void k_pool_conv(
    const float* __restrict__ fb, const float* __restrict__ wconv,
    const float* __restrict__ bconv, bf16* __restrict__ Y) {
  __shared__ float wS[64 * 65], bS[64], Xs[4096];
  int tid = threadIdx.x;
  int b = blockIdx.x >> 8, tile = blockIdx.x & 255;
  int n0 = tile * 64;
  for (int i = tid; i < 4096; i += 256) wS[(i >> 6) * 65 + (i & 63)] = wconv[i];
  if (tid < 64) bS[tid] = bconv[tid];
  for (int i = tid; i < 4096; i += 256) {
    int c = i >> 6, px = i & 63;
    int n = n0 + px, h = n >> 7, w = n & 127;
    size_t fbase = ((size_t)((b * 64 + c) * 256 + 2 * h)) * 256 + 2 * w;
    float2 v01 = *(const float2*)(fb + fbase);
    float2 v23 = *(const float2*)(fb + fbase + 256);
    Xs[i] = fmaxf(fmaxf(v01.x, v01.y), fmaxf(v23.x, v23.y));
  }
  __syncthreads();
  int ty = tid >> 4, tx = tid & 15;
  float acc[4][4];
#pragma unroll
  for (int i = 0; i < 4; ++i) {
    float bv = bS[ty + 16 * i];
#pragma unroll
    for (int j = 0; j < 4; ++j) acc[i][j] = bv;
  }
  for (int c = 0; c < 64; ++c) {
    float xv[4], wv[4];
#pragma unroll
    for (int j = 0; j < 4; ++j) xv[j] = Xs[c * 64 + tx * 4 + j];
#pragma unroll
    for (int i = 0; i < 4; ++i) wv[i] = wS[(ty + 16 * i) * 65 + c];
#pragma unroll
    for (int i = 0; i < 4; ++i)
#pragma unroll
      for (int j = 0; j < 4; ++j) acc[i][j] = fmaf(wv[i], xv[j], acc[i][j]);
  }
#pragma unroll
  for (int i = 0; i < 4; ++i) {
    int ch = ty + 16 * i;
    bf16* yb = Y + (size_t)(b * 64 + ch) * NP + n0 + tx * 4;
#pragma unroll
    for (int j = 0; j < 4; ++j) yb[j] = f2bf(acc[i][j]);
  }
}

// ---------------------------------------------------------------------------
// K2a: stats stage 1. 512 blocks; each reduces 8192 contiguous bf16 of one
// (channel, batch, half) slab with ushort8 loads. PS[blk]=sum, PS[512+blk]=sq.
// ---------------------------------------------------------------------------
__global__ __launch_bounds__(256) void k_stats_p1(const bf16* __restrict__ Y,
                                                  float* __restrict__ PS) {
  int blk = blockIdx.x, tid = threadIdx.x;
  int o = blk >> 3, slab = blk & 7;
  int b = slab >> 1, half = slab & 1;
  const us8* vp =
      (const us8*)(Y + ((size_t)(b * 64 + o)) * NP + half * 8192);
  float s = 0.f, ss = 0.f;
#pragma unroll
  for (int it = 0; it < 4; ++it) {
    us8 v = vp[tid + 256 * it];
#pragma unroll
    for (int e = 0; e < 8; ++e) {
      float f = bfu(v[e]);
      s += f;
      ss = fmaf(f, f, ss);
    }
  }
  for (int off = 32; off > 0; off >>= 1) {
    s += __shfl_down(s, off, 64);
    ss += __shfl_down(ss, off, 64);
  }
  __shared__ float sh[8];
  int wv = tid >> 6, ln = tid & 63;
  if (ln == 0) { sh[wv] = s; sh[4 + wv] = ss; }
  __syncthreads();
  if (tid == 0) {
    PS[blk] = sh[0] + sh[1] + sh[2] + sh[3];
    PS[512 + blk] = sh[4] + sh[5] + sh[6] + sh[7];
  }
}

// K2b: stats stage 2 + BN scale/shift + scalar header (fused)
__global__ __launch_bounds__(64) void k_stats_p2(
    const float* __restrict__ PS, const float* __restrict__ bng,
    const float* __restrict__ bnb, float* __restrict__ SCALE,
    float* __restrict__ SHIFT, const float* xg, const float* fg,
    const float* pg, const float* pg2, const float* cg,
    float* __restrict__ HDR) {
  int o = threadIdx.x;
  float s = 0.f, ss = 0.f;
#pragma unroll
  for (int k = 0; k < 8; ++k) {
    s += PS[o * 8 + k];
    ss += PS[512 + o * 8 + k];
  }
  const float inv = 1.0f / (NB * NP);
  float mu = s * inv;
  float var = ss * inv - mu * mu;
  float r = rsqrtf(var + 1e-5f);
  float sc = r * bng[o];
  SCALE[o] = sc;
  SHIFT[o] = bnb[o] - mu * sc;
  if (o == 0) {
    float vpg = pg[0];
    HDR[1] = vpg * xg[0];
    HDR[2] = pg2[0] * fg[0];
    HDR[3] = 2.0f + vpg;
    HDR[4] = pg2[0];
    HDR[5] = cg[0];
  }
}

// ---------------------------------------------------------------------------
// K4: fused q|k|v conv1x1: 80 out-ch x 128 px, 5x8 thread tile.
// Xs staged as u16 bf16 (LDS 37 KB -> 4 blocks/CU). wS stride 65.
// ---------------------------------------------------------------------------
template <bool BN>
__global__ __launch_bounds__(256) void k_conv80(
    const void* __restrict__ inp, const float* __restrict__ SCALE,
    const float* __restrict__ SHIFT,
    const float* __restrict__ qw, const float* __restrict__ qb,
    const float* __restrict__ kw, const float* __restrict__ kb,
    const float* __restrict__ vw, const float* __restrict__ vb,
    bf16* __restrict__ Q, bf16* __restrict__ K, bf16* __restrict__ V) {
  __shared__ float wS[80 * 65], bS[80];
  __shared__ u16 Xs[8192];
  int tid = threadIdx.x;
  int b = blockIdx.x >> 7, tile = blockIdx.x & 127;
  int n0 = tile * 128;
  for (int i = tid; i < 512; i += 256) {
    wS[(i >> 6) * 65 + (i & 63)] = qw[i];
    wS[(8 + (i >> 6)) * 65 + (i & 63)] = kw[i];
  }
  for (int i = tid; i < 4096; i += 256)
    wS[(16 + (i >> 6)) * 65 + (i & 63)] = vw[i];
  if (tid < 8) { bS[tid] = qb[tid]; bS[8 + tid] = kb[tid]; }
  if (tid < 64) bS[16 + tid] = vb[tid];
  for (int i = tid; i < 8192; i += 256) {
    int c = i >> 7, px = i & 127;
    size_t idx = (size_t)(b * 64 + c) * NP + n0 + px;
    float v;
    if (BN) {
      v = bf2f(((const bf16*)inp)[idx]);
      v = fmaf(v, SCALE[c], SHIFT[c]);
      v = fmaxf(v, 0.f);
    } else {
      v = ((const float*)inp)[idx];
    }
    Xs[i] = fbu(v);
  }
  __syncthreads();
  int ty = tid >> 4, tx = tid & 15;
  float acc[5][8];
#pragma unroll
  for (int i = 0; i < 5; ++i) {
    float bv = bS[ty + 16 * i];
#pragma unroll
    for (int j = 0; j < 8; ++j) acc[i][j] = bv;
  }
  for (int c = 0; c < 64; ++c) {
    float xv[8], wv[5];
#pragma unroll
    for (int j = 0; j < 8; ++j) xv[j] = bfu(Xs[c * 128 + tx + 16 * j]);
#pragma unroll
    for (int i = 0; i < 5; ++i) wv[i] = wS[(ty + 16 * i) * 65 + c];
#pragma unroll
    for (int i = 0; i < 5; ++i)
#pragma unroll
      for (int j = 0; j < 8; ++j) acc[i][j] = fmaf(wv[i], xv[j], acc[i][j]);
  }
#pragma unroll
  for (int i = 0; i < 5; ++i) {
    int ch = ty + 16 * i;
    bf16* dst;
    size_t base;
    if (ch < 8) { dst = Q; base = (size_t)(b * 8 + ch) * NP; }
    else if (ch < 16) { dst = K; base = (size_t)(b * 8 + ch - 8) * NP; }
    else { dst = V; base = (size_t)(b * 64 + ch - 16) * NP; }
#pragma unroll
    for (int j = 0; j < 8; ++j) dst[base + n0 + tx + 16 * j] = f2bf(acc[i][j]);
  }
}

// ---------------------------------------------------------------------------
// K5: 128x128 bf16 plane transpose (also covers Q+K in one call: contiguous)
// ---------------------------------------------------------------------------
__global__ __launch_bounds__(256) void k_transpose(const u16* __restrict__ in,
                                                   u16* __restrict__ out) {
  int tileId = blockIdx.x & 15;
  int plane = blockIdx.x >> 4;
  int th = tileId >> 2, tw = tileId & 3;
  __shared__ u16 t[32][33];
  int lx = threadIdx.x & 31, ly = threadIdx.x >> 5;
  const u16* ip = in + (size_t)plane * NP;
  for (int i = 0; i < 32; i += 8)
    t[ly + i][lx] = ip[(size_t)(th * 32 + ly + i) * 128 + tw * 32 + lx];
  __syncthreads();
  u16* op = out + (size_t)plane * NP;
  for (int i = 0; i < 32; i += 8)
    op[(size_t)(tw * 32 + ly + i) * 128 + th * 32 + lx] = t[lx][ly + i];
}

// ---------------------------------------------------------------------------
// K6a: e_w per-row max/sumexp -> raw stats into MW/LW
// ---------------------------------------------------------------------------
__global__ __launch_bounds__(256) void k_ew_stats(
    const bf16* __restrict__ Q, const bf16* __restrict__ K,
    float* __restrict__ MW, float* __restrict__ LW) {
  int b = blockIdx.x >> 7, h = blockIdx.x & 127;
  __shared__ float qs[1024], ks[1024], red[256];
  int tid = threadIdx.x;
  for (int i = tid; i < 1024; i += 256) {
    int c = i >> 7, j = i & 127;
    size_t idx = (size_t)(b * 8 + c) * NP + (size_t)h * 128 + j;
    qs[i] = bf2f(Q[idx]);
    ks[i] = bf2f(K[idx]);
  }
  __syncthreads();
  int w = tid & 127, half = tid >> 7;
  float qr[8];
#pragma unroll
  for (int c = 0; c < 8; ++c) qr[c] = qs[c * 128 + w];
  float m = -3.0e38f;
  for (int v0 = 0; v0 < 64; ++v0) {
    int v = half * 64 + v0;
    float s = 0.f;
#pragma unroll
    for (int c = 0; c < 8; ++c) s = fmaf(qr[c], ks[c * 128 + v], s);
    m = fmaxf(m, s);
  }
  red[tid] = m;
  __syncthreads();
  float mj = fmaxf(red[w], red[128 + w]);
  __syncthreads();
  float l = 0.f;
  for (int v0 = 0; v0 < 64; ++v0) {
    int v = half * 64 + v0;
    float s = 0.f;
#pragma unroll
    for (int c = 0; c < 8; ++c) s = fmaf(qr[c], ks[c * 128 + v], s);
    l += __expf(s - mj);
  }
  red[tid] = l;
  __syncthreads();
  if (half == 0) {
    size_t o = (size_t)b * NP + (size_t)h * 128 + w;
    MW[o] = mj;
    LW[o] = red[w] + red[128 + w];
  }
}

// ---------------------------------------------------------------------------
// K6b: e_h per-row stats (diag masked) + in-place combine -> MW=M, LW=1/L
// ---------------------------------------------------------------------------
__global__ __launch_bounds__(256) void k_eh_combine(
    const bf16* __restrict__ QT, const bf16* __restrict__ KT,
    float* __restrict__ MW, float* __restrict__ LW) {
  int b = blockIdx.x >> 7, w = blockIdx.x & 127;
  __shared__ float qs[1024], ks[1024], red[256];
  int tid = threadIdx.x;
  for (int i = tid; i < 1024; i += 256) {
    int c = i >> 7, j = i & 127;
    size_t idx = (size_t)(b * 8 + c) * NP + (size_t)w * 128 + j;
    qs[i] = bf2f(QT[idx]);
    ks[i] = bf2f(KT[idx]);
  }
  __syncthreads();
  int h = tid & 127, half = tid >> 7;
  float qr[8];
#pragma unroll
  for (int c = 0; c < 8; ++c) qr[c] = qs[c * 128 + h];
  float m = -3.0e38f;
  for (int g0 = 0; g0 < 64; ++g0) {
    int g = half * 64 + g0;
    float s = 0.f;
#pragma unroll
    for (int c = 0; c < 8; ++c) s = fmaf(qr[c], ks[c * 128 + g], s);
    if (g == h) s = -1.0e30f;
    m = fmaxf(m, s);
  }
  red[tid] = m;
  __syncthreads();
  float mj = fmaxf(red[h], red[128 + h]);
  __syncthreads();
  float l = 0.f;
  for (int g0 = 0; g0 < 64; ++g0) {
    int g = half * 64 + g0;
    float s = 0.f;
#pragma unroll
    for (int c = 0; c < 8; ++c) s = fmaf(qr[c], ks[c * 128 + g], s);
    l += (g == h) ? 0.f : __expf(s - mj);
  }
  red[tid] = l;
  __syncthreads();
  if (half == 0) {
    size_t o = (size_t)b * NP + (size_t)h * 128 + w;
    float lh = red[h] + red[128 + h];
    float mw = MW[o], lw = LW[o];
    float mm = fmaxf(mw, mj);
    float ll = lw * __expf(mw - mm) + lh * __expf(mj - mm);
    MW[o] = mm;
    LW[o] = 1.0f / ll;
  }
}

// ---------------------------------------------------------------------------
// K7: out_w. Block (b,h). LDS u16 V/q/k (38 KB -> 4 blocks/CU).
// ACC (fp32 d_out) (+)= sc*out_w, contiguous writes.
// ---------------------------------------------------------------------------
__global__ __launch_bounds__(128) void k_av_w(
    const bf16* __restrict__ Q, const bf16* __restrict__ K,
    const bf16* __restrict__ V, const float* __restrict__ M,
    const float* __restrict__ LI, float* __restrict__ ACC,
    const float* __restrict__ HDR, int scIdx, int accum) {
  int b = blockIdx.x >> 7, h = blockIdx.x & 127;
  __shared__ u16 qrow[8 * 128], krow[8 * 128];
  __shared__ u16 Vs[64 * 130];
  __shared__ float As[32 * 129];
  __shared__ float Ml[128], Li[128];
  int tid = threadIdx.x;
  {  // q/k rows: 1024 u16 each = one us8 load per thread
    int c = tid >> 4, vj = tid & 15;
    const us8* qp = (const us8*)(Q + ((size_t)(b * 8 + c)) * NP + (size_t)h * 128);
    const us8* kp = (const us8*)(K + ((size_t)(b * 8 + c)) * NP + (size_t)h * 128);
    us8 qv = qp[vj], kv = kp[vj];
#pragma unroll
    for (int e = 0; e < 8; ++e) {
      qrow[c * 128 + vj * 8 + e] = qv[e];
      krow[c * 128 + vj * 8 + e] = kv[e];
    }
  }
  for (int i2 = tid; i2 < 1024; i2 += 128) {  // V: 8192 u16, us8 loads
    int c = i2 >> 4, vj = i2 & 15;
    const us8* vp =
        (const us8*)(V + ((size_t)(b * 64 + c)) * NP + (size_t)h * 128);
    us8 vv = vp[vj];
#pragma unroll
    for (int e = 0; e < 8; ++e) Vs[c * 130 + vj * 8 + e] = vv[e];
  }
  Ml[tid] = M[(size_t)b * NP + (size_t)h * 128 + tid];
  Li[tid] = LI[(size_t)b * NP + (size_t)h * 128 + tid];
  float sc = HDR[scIdx];
  int ig = tid & 7, cg = tid >> 3, c0 = cg * 4;
  int ar = tid >> 2, av = tid & 3;
  float* accBase = ACC + (size_t)(b * 64) * NP + (size_t)h * 128;
  for (int chunk = 0; chunk < 4; ++chunk) {
    __syncthreads();
    {
      int w = chunk * 32 + ar;
      float mv = Ml[w], li = Li[w];
      float qr[8];
#pragma unroll
      for (int c = 0; c < 8; ++c) qr[c] = bfu(qrow[c * 128 + w]);
      for (int k = 0; k < 32; ++k) {
        int v = av * 8 + (k & 7) + (k >> 3) * 32;
        float s = 0.f;
#pragma unroll
        for (int c = 0; c < 8; ++c) s = fmaf(qr[c], bfu(krow[c * 128 + v]), s);
        As[ar * 129 + v] = __expf(s - mv) * li;
      }
    }
    __syncthreads();
    float acc[4][4];
#pragma unroll
    for (int ii = 0; ii < 4; ++ii)
#pragma unroll
      for (int cc = 0; cc < 4; ++cc) acc[ii][cc] = 0.f;
    for (int j = 0; j < 128; ++j) {
      float a[4], vv[4];
#pragma unroll
      for (int ii = 0; ii < 4; ++ii) a[ii] = As[(ig * 4 + ii) * 129 + j];
#pragma unroll
      for (int cc = 0; cc < 4; ++cc) vv[cc] = bfu(Vs[(c0 + cc) * 130 + j]);
#pragma unroll
      for (int ii = 0; ii < 4; ++ii)
#pragma unroll
        for (int cc = 0; cc < 4; ++cc) acc[ii][cc] = fmaf(a[ii], vv[cc], acc[ii][cc]);
    }
    int i0 = chunk * 32 + ig * 4;
#pragma unroll
    for (int ii = 0; ii < 4; ++ii)
#pragma unroll
      for (int cc = 0; cc < 4; ++cc) {
        size_t oidx = (size_t)(c0 + cc) * NP + (size_t)(i0 + ii);
        float val = sc * acc[ii][cc];
        accBase[oidx] = (accum ? accBase[oidx] : 0.f) + val;
      }
  }
}

// ---------------------------------------------------------------------------
// K8: out_h. Block (b,w). Writes OHT[b][c][w][h] (contiguous bf16, no RMW).
// ---------------------------------------------------------------------------
__global__ __launch_bounds__(128) void k_av_h(
    const bf16* __restrict__ QT, const bf16* __restrict__ KT,
    const bf16* __restrict__ VT, const float* __restrict__ M,
    const float* __restrict__ LI, bf16* __restrict__ OHT) {
  int b = blockIdx.x >> 7, w = blockIdx.x & 127;
  __shared__ u16 qcol[8 * 128], kcol[8 * 128];
  __shared__ u16 Vs[64 * 130];
  __shared__ float As[32 * 129];
  __shared__ float Ml[128], Li[128];
  int tid = threadIdx.x;
  {
    int c = tid >> 4, vj = tid & 15;
    const us8* qp = (const us8*)(QT + ((size_t)(b * 8 + c)) * NP + (size_t)w * 128);
    const us8* kp = (const us8*)(KT + ((size_t)(b * 8 + c)) * NP + (size_t)w * 128);
    us8 qv = qp[vj], kv = kp[vj];
#pragma unroll
    for (int e = 0; e < 8; ++e) {
      qcol[c * 128 + vj * 8 + e] = qv[e];
      kcol[c * 128 + vj * 8 + e] = kv[e];
    }
  }
  for (int i2 = tid; i2 < 1024; i2 += 128) {
    int c = i2 >> 4, vj = i2 & 15;
    const us8* vp =
        (const us8*)(VT + ((size_t)(b * 64 + c)) * NP + (size_t)w * 128);
    us8 vv = vp[vj];
#pragma unroll
    for (int e = 0; e < 8; ++e) Vs[c * 130 + vj * 8 + e] = vv[e];
  }
  Ml[tid] = M[(size_t)b * NP + (size_t)tid * 128 + w];
  Li[tid] = LI[(size_t)b * NP + (size_t)tid * 128 + w];
  int ig = tid & 7, cg = tid >> 3, c0 = cg * 4;
  int ar = tid >> 2, av = tid & 3;
  bf16* outBase = OHT + (size_t)(b * 64) * NP + (size_t)w * 128;
  for (int chunk = 0; chunk < 4; ++chunk) {
    __syncthreads();
    {
      int hh = chunk * 32 + ar;
      float mv = Ml[hh], li = Li[hh];
      float qr[8];
#pragma unroll
      for (int c = 0; c < 8; ++c) qr[c] = bfu(qcol[c * 128 + hh]);
      for (int k = 0; k < 32; ++k) {
        int g = av * 8 + (k & 7) + (k >> 3) * 32;
        float s = 0.f;
#pragma unroll
        for (int c = 0; c < 8; ++c) s = fmaf(qr[c], bfu(kcol[c * 128 + g]), s);
        As[ar * 129 + g] = (g == hh) ? 0.f : __expf(s - mv) * li;
      }
    }
    __syncthreads();
    float acc[4][4];
#pragma unroll
    for (int ii = 0; ii < 4; ++ii)
#pragma unroll
      for (int cc = 0; cc < 4; ++cc) acc[ii][cc] = 0.f;
    for (int j = 0; j < 128; ++j) {
      float a[4], vv[4];
#pragma unroll
      for (int ii = 0; ii < 4; ++ii) a[ii] = As[(ig * 4 + ii) * 129 + j];
#pragma unroll
      for (int cc = 0; cc < 4; ++cc) vv[cc] = bfu(Vs[(c0 + cc) * 130 + j]);
#pragma unroll
      for (int ii = 0; ii < 4; ++ii)
#pragma unroll
        for (int cc = 0; cc < 4; ++cc) acc[ii][cc] = fmaf(a[ii], vv[cc], acc[ii][cc]);
    }
    int i0 = chunk * 32 + ig * 4;
#pragma unroll
    for (int ii = 0; ii < 4; ++ii)
#pragma unroll
      for (int cc = 0; cc < 4; ++cc) {
        size_t oidx = (size_t)(c0 + cc) * NP + (size_t)(i0 + ii);
        outBase[oidx] = f2bf(acc[ii][cc]);
      }
  }
}

// ---------------------------------------------------------------------------
// K8b: transpose-add: ACC[b][c][h][w] += sc * OHT[b][c][w][h]. 32x32 LDS.
// ---------------------------------------------------------------------------
__global__ __launch_bounds__(256) void k_merge(const bf16* __restrict__ OHT,
                                               float* __restrict__ ACC,
                                               const float* __restrict__ HDR,
                                               int scIdx) {
  int tileId = blockIdx.x & 15;
  int plane = blockIdx.x >> 4;
  int th = tileId >> 2, tw = tileId & 3;
  __shared__ float t[32][33];
  int lx = threadIdx.x & 31, ly = threadIdx.x >> 5;
  const bf16* ip = OHT + (size_t)plane * NP;
  for (int i = 0; i < 32; i += 8)
    t[ly + i][lx] = bf2f(ip[(size_t)(th * 32 + ly + i) * 128 + tw * 32 + lx]);
  __syncthreads();
  float sc = HDR[scIdx];
  float* op = ACC + (size_t)plane * NP;
  for (int i = 0; i < 32; i += 8) {
    int h = tw * 32 + ly + i, w = th * 32 + lx;
    op[(size_t)h * 128 + w] += sc * t[lx][ly + i];
  }
}

// ---------------------------------------------------------------------------
// K9: partial Gram of y=BN(Y) applied at staging
// ---------------------------------------------------------------------------
__global__ __launch_bounds__(256) void k_gram(const bf16* __restrict__ Y,
                                              const float* __restrict__ SCALE,
                                              const float* __restrict__ SHIFT,
                                              float* __restrict__ GP) {
  int b = blockIdx.x >> 5, ch = blockIdx.x & 31;
  int tid = threadIdx.x;
  __shared__ float fs[64 * 129];
  int cg = tid >> 4, dg = tid & 15;
  float acc[4][4];
#pragma unroll
  for (int i = 0; i < 4; ++i)
#pragma unroll
    for (int jx = 0; jx < 4; ++jx) acc[i][jx] = 0.f;
  const bf16* yb = Y + (size_t)b * 64 * NP + ch * 512;
  for (int t = 0; t < 4; ++t) {
    __syncthreads();
    for (int idx = tid; idx < 8192; idx += 256) {
      int c = idx >> 7, j = idx & 127;
      float v = fmaf(bf2f(yb[(size_t)c * NP + t * 128 + j]), SCALE[c], SHIFT[c]);
      fs[c * 129 + j] = fmaxf(v, 0.f);
    }
    __syncthreads();
    for (int j = 0; j < 128; ++j) {
      float a[4], d[4];
#pragma unroll
      for (int i = 0; i < 4; ++i) a[i] = fs[(cg * 4 + i) * 129 + j];
#pragma unroll
      for (int i = 0; i < 4; ++i) d[i] = fs[(dg * 4 + i) * 129 + j];
#pragma unroll
      for (int i = 0; i < 4; ++i)
#pragma unroll
        for (int jx = 0; jx < 4; ++jx) acc[i][jx] = fmaf(a[i], d[jx], acc[i][jx]);
    }
  }
  float* gp = GP + ((size_t)b * 32 + ch) * 4096;
#pragma unroll
  for (int i = 0; i < 4; ++i)
#pragma unroll
    for (int jx = 0; jx < 4; ++jx)
      gp[(cg * 4 + i) * 64 + dg * 4 + jx] = acc[i][jx];
}

// K10: reduce Gram partials; row softmax of (max-E)
__global__ __launch_bounds__(256) void k_gram_reduce(const float* __restrict__ GP,
                                                     float* __restrict__ CATT) {
  int b = blockIdx.x, tid = threadIdx.x;
  __shared__ float Es[4096];
  for (int e = tid; e < 4096; e += 256) {
    float s = 0.f;
    for (int k = 0; k < 32; ++k) s += GP[((size_t)b * 32 + k) * 4096 + e];
    Es[e] = s;
  }
  __syncthreads();
  int wv = tid >> 6, ln = tid & 63;
  for (int r = wv; r < 64; r += 4) {
    float v = Es[r * 64 + ln];
    float mn = v;
    for (int off = 32; off; off >>= 1) mn = fminf(mn, __shfl_xor(mn, off, 64));
    float e = __expf(mn - v);
    float s = e;
    for (int off = 32; off; off >>= 1) s += __shfl_xor(s, off, 64);
    CATT[((size_t)b * 64 + r) * 64 + ln] = e / s;
  }
}

// ---------------------------------------------------------------------------
// K11: out = (2+pg)*x + pg2*y + ACC + cg*(catt@y). In-place fp32 on d_out.
// ---------------------------------------------------------------------------
__global__ __launch_bounds__(256) void k_final(
    const float* __restrict__ x, const bf16* __restrict__ Y,
    const float* __restrict__ SCALE, const float* __restrict__ SHIFT,
    const float* __restrict__ CATT, const float* __restrict__ HDR,
    float* __restrict__ OUT) {
  __shared__ float attS[64 * 65], Ys[64 * 65];
  int tid = threadIdx.x;
  int b = blockIdx.x >> 8, tile = blockIdx.x & 255;
  int n0 = tile * 64;
  for (int i = tid; i < 4096; i += 256)
    attS[(i >> 6) * 65 + (i & 63)] = CATT[(size_t)b * 4096 + i];
  for (int i = tid; i < 4096; i += 256) {
    int d = i >> 6, px = i & 63;
    float v = fmaf(bf2f(Y[(size_t)(b * 64 + d) * NP + n0 + px]), SCALE[d], SHIFT[d]);
    Ys[d * 65 + px] = fmaxf(v, 0.f);
  }
  __syncthreads();
  int cg = tid >> 4, pgx = tid & 15;
  int c0 = cg * 4, p0 = pgx * 4;
  float acc[4][4];
#pragma unroll
  for (int i = 0; i < 4; ++i)
#pragma unroll
    for (int j = 0; j < 4; ++j) acc[i][j] = 0.f;
  for (int d = 0; d < 64; ++d) {
    float a[4], yv[4];
#pragma unroll
    for (int i = 0; i < 4; ++i) a[i] = attS[(c0 + i) * 65 + d];
#pragma unroll
    for (int j = 0; j < 4; ++j) yv[j] = Ys[d * 65 + p0 + j];
#pragma unroll
    for (int i = 0; i < 4; ++i)
#pragma unroll
      for (int j = 0; j < 4; ++j) acc[i][j] = fmaf(a[i], yv[j], acc[i][j]);
  }
  float c2pg = HDR[3], fpg2 = HDR[4], fcg = HDR[5];
#pragma unroll
  for (int i = 0; i < 4; ++i) {
    size_t base = (size_t)(b * 64 + c0 + i) * NP + n0 + p0;
#pragma unroll
    for (int j = 0; j < 4; ++j) {
      float yv = Ys[(c0 + i) * 65 + p0 + j];
      OUT[base + j] =
          c2pg * x[base + j] + fpg2 * yv + OUT[base + j] + fcg * acc[i][j];
    }
  }
}

// ---------------------------------------------------------------------------
extern "C" void kernel_launch(void* const* d_in, const int* in_sizes, int n_in,
                              void* d_out, int out_size, void* d_ws, size_t ws_size,
                              hipStream_t stream) {
  const float* x = (const float*)d_in[0];
  const float* fbp = (const float*)d_in[1];

  // Workspace: 38,277,120 bytes total (proven extent).
  char* base = (char*)d_ws;
  float* HDR = (float*)base;
  float* SCALE = HDR + 16;
  float* SHIFT = SCALE + 64;
  char* p = base + 4096;
  bf16* Y = (bf16*)p;   p += 8388608;
  bf16* Q = (bf16*)p;   p += 1048576;
  bf16* K = (bf16*)p;   p += 1048576;
  bf16* QT = (bf16*)p;  p += 1048576;
  bf16* KT = (bf16*)p;  p += 1048576;
  bf16* V = (bf16*)p;   p += 8388608;
  bf16* VT = (bf16*)p;  p += 8388608;
  float* MW = (float*)p; p += 262144;   // joint M after combine
  float* LW = (float*)p; p += 262144;   // joint 1/L after combine
  bf16* OHT = (bf16*)p;  p += 8388608;  // out_h in [b][c][w][h] layout
  float* ACC = (float*)d_out;           // fp32, 16 MB
  float* PS = (float*)Q;     // stats partials (4 KB), Q unused until conv80
  float* GP = (float*)Q;     // Gram partials after module loop
  float* CATT = (float*)QT;  // reuses QT

  k_pool_conv<<<1024, 256, 0, stream>>>(fbp, (const float*)d_in[2],
                                        (const float*)d_in[3], Y);
  k_stats_p1<<<512, 256, 0, stream>>>(Y, PS);
  k_stats_p2<<<1, 64, 0, stream>>>(PS, (const float*)d_in[4],
                                   (const float*)d_in[5], SCALE, SHIFT,
                                   (const float*)d_in[12], (const float*)d_in[19],
                                   (const float*)d_in[20], (const float*)d_in[21],
                                   (const float*)d_in[22], HDR);

  for (int m = 0; m < 2; ++m) {
    const float *qw, *qb, *kw, *kb, *vw, *vb;
    if (m == 0) {
      qw = (const float*)d_in[6]; qb = (const float*)d_in[7];
      kw = (const float*)d_in[8]; kb = (const float*)d_in[9];
      vw = (const float*)d_in[10]; vb = (const float*)d_in[11];
    } else {
      qw = (const float*)d_in[13]; qb = (const float*)d_in[14];
      kw = (const float*)d_in[15]; kb = (const float*)d_in[16];
      vw = (const float*)d_in[17]; vb = (const float*)d_in[18];
    }
    if (m == 0)
      k_conv80<false><<<512, 256, 0, stream>>>(x, SCALE, SHIFT, qw, qb, kw, kb,
                                               vw, vb, Q, K, V);
    else
      k_conv80<true><<<512, 256, 0, stream>>>(Y, SCALE, SHIFT, qw, qb, kw, kb,
                                              vw, vb, Q, K, V);
    // Q,K contiguous and QT,KT contiguous: one call transposes both (64 planes)
    k_transpose<<<1024, 256, 0, stream>>>((const u16*)Q, (u16*)QT);
    k_transpose<<<4096, 256, 0, stream>>>((const u16*)V, (u16*)VT);
    k_ew_stats<<<512, 256, 0, stream>>>(Q, K, MW, LW);
    k_eh_combine<<<512, 256, 0, stream>>>(QT, KT, MW, LW);
    k_av_w<<<512, 128, 0, stream>>>(Q, K, V, MW, LW, ACC, HDR, 1 + m, m);
    k_av_h<<<512, 128, 0, stream>>>(QT, KT, VT, MW, LW, OHT);
    k_merge<<<4096, 256, 0, stream>>>(OHT, ACC, HDR, 1 + m);
  }

  k_gram<<<128, 256, 0, stream>>>(Y, SCALE, SHIFT, GP);
  k_gram_reduce<<<4, 256, 0, stream>>>(GP, CATT);
  k_final<<<1024, 256, 0, stream>>>(x, Y, SCALE, SHIFT, CATT, HDR,
                                    (float*)d_out);
}